// Round 6
// baseline (648.677 us; speedup 1.0000x reference)
//
#include <hip/hip_runtime.h>
#include <stdint.h>

typedef __bf16 bf16;
typedef __bf16 bf16x4 __attribute__((ext_vector_type(4)));
typedef __bf16 bf16x8 __attribute__((ext_vector_type(8)));
typedef float  f32x4  __attribute__((ext_vector_type(4)));

#define DEVI __device__ __forceinline__

DEVI void gll16(const void* g, void* l) {
  __builtin_amdgcn_global_load_lds(
      (const __attribute__((address_space(1))) void*)g,
      (__attribute__((address_space(3))) void*)l,
      16, 0, 0);
}

DEVI f32x4 mfma16(bf16x8 a, bf16x8 b, f32x4 c) {
  return __builtin_amdgcn_mfma_f32_16x16x32_bf16(a, b, c, 0, 0, 0);
}

// ---------------- elementwise ----------------
__global__ void k_copy_f32(const float* __restrict__ in, float* __restrict__ out, int n4) {
  int i = blockIdx.x * 256 + threadIdx.x;
  if (i < n4) ((f32x4*)out)[i] = ((const f32x4*)in)[i];
}

__global__ void k_conv_bf16(const float* __restrict__ in, bf16* __restrict__ out, int n4) {
  int i = blockIdx.x * 256 + threadIdx.x;
  if (i < n4) {
    f32x4 v = ((const f32x4*)in)[i];
    bf16x4 o;
    o[0] = (bf16)v[0]; o[1] = (bf16)v[1]; o[2] = (bf16)v[2]; o[3] = (bf16)v[3];
    ((bf16x4*)out)[i] = o;
  }
}

__global__ void k_concat2(const float* __restrict__ a, const float* __restrict__ b,
                          float* __restrict__ out, int n) {
  int i = blockIdx.x * 256 + threadIdx.x;
  if (i < n) out[i] = a[i];
  else if (i < 2 * n) out[i] = b[i - n];
}

// ------------- weight fp32 [K][N] -> bf16 W^T [N][K] -------------
__global__ void k_wt(const float* __restrict__ W, bf16* __restrict__ WT, int K, int N) {
  __shared__ float t[32][33];
  int bn = blockIdx.x * 32, bk = blockIdx.y * 32;
  int tx = threadIdx.x, ty = threadIdx.y;
#pragma unroll
  for (int i = 0; i < 4; ++i)
    t[ty + i * 8][tx] = W[(size_t)(bk + ty + i * 8) * N + bn + tx];
  __syncthreads();
#pragma unroll
  for (int i = 0; i < 4; ++i)
    WT[(size_t)(bn + ty + i * 8) * K + bk + tx] = (bf16)t[tx][ty + i * 8];
}

// ------------- bf16 V-slab transpose: src rows b*Tlen+t, col colofs+h*64+d  ->  dst[hb][64][Tlen] -------------
__global__ void k_vt(const bf16* __restrict__ src, int ld, int colofs, int Tlen,
                     bf16* __restrict__ dst) {
  __shared__ bf16 t[32][33];
  int t0 = blockIdx.x * 32, d0 = blockIdx.y * 32, hb = blockIdx.z;
  int b = hb >> 4, h = hb & 15;
  int tx = threadIdx.x, ty = threadIdx.y;
  const bf16* s = src + (size_t)(b * Tlen + t0) * ld + colofs + h * 64 + d0;
#pragma unroll
  for (int i = 0; i < 4; ++i)
    t[ty + i * 8][tx] = s[(size_t)(ty + i * 8) * ld + tx];
  __syncthreads();
  bf16* o = dst + ((size_t)hb * 64 + d0) * Tlen + t0;
#pragma unroll
  for (int i = 0; i < 4; ++i)
    o[(size_t)(ty + i * 8) * Tlen + tx] = t[tx][ty + i * 8];
}

// ---------------- layernorm (C=1024) fp32 -> bf16 ----------------
__global__ __launch_bounds__(256)
void k_ln(const float* __restrict__ x, const float* __restrict__ g,
          const float* __restrict__ b, bf16* __restrict__ out) {
  int row = blockIdx.x, tid = threadIdx.x;
  f32x4 v = ((const f32x4*)(x + (size_t)row * 1024))[tid];
  float s = v[0] + v[1] + v[2] + v[3];
  float sq = v[0]*v[0] + v[1]*v[1] + v[2]*v[2] + v[3]*v[3];
#pragma unroll
  for (int m = 1; m < 64; m <<= 1) {
    s  += __shfl_xor(s, m, 64);
    sq += __shfl_xor(sq, m, 64);
  }
  __shared__ float ps[4], psq[4];
  int w = tid >> 6;
  if ((tid & 63) == 0) { ps[w] = s; psq[w] = sq; }
  __syncthreads();
  s  = ps[0] + ps[1] + ps[2] + ps[3];
  sq = psq[0] + psq[1] + psq[2] + psq[3];
  float mean = s * (1.f / 1024.f);
  float rs = rsqrtf(sq * (1.f / 1024.f) - mean * mean + 1e-5f);
  f32x4 gv = ((const f32x4*)g)[tid];
  f32x4 bv = ((const f32x4*)b)[tid];
  bf16x4 o;
#pragma unroll
  for (int i = 0; i < 4; ++i) o[i] = (bf16)((v[i] - mean) * rs * gv[i] + bv[i]);
  ((bf16x4*)(out + (size_t)row * 1024))[tid] = o;
}

// ---------------- GEMM small-tile: BM=64 BN=128 BK=64, 2-phase, 3 blk/CU ----------------
template <int EPI>
__global__ __launch_bounds__(256, 3)
void k_gemm_s(const bf16* __restrict__ A, const bf16* __restrict__ BT,
              const float* __restrict__ bias, void* __restrict__ Cout,
              int M, int N, int K) {
  __shared__ __align__(16) char SA[2][8192];
  __shared__ __align__(16) char SB[2][16384];
  const int tid = threadIdx.x;
  const int lane = tid & 63;
  const int w = tid >> 6;
  const int wr = w >> 1, wc = w & 1;
  const int lr = lane & 15, lg = lane >> 4;
  const int nk = K >> 6;

  const int nwg = gridDim.x;
  const int q = nwg >> 3, r = nwg & 7;
  const int xcd = blockIdx.x & 7, loc = blockIdx.x >> 3;
  const int wg = (xcd < r ? xcd * (q + 1) : r * (q + 1) + (xcd - r) * q) + loc;
  const int gy = M >> 6;
  const int m0 = (wg % gy) << 6, n0 = (wg / gy) << 7;

  const int c8 = tid & 7;
  const int hrb = tid >> 3;
  auto stgA = [&](int buf, int ktc) {
#pragma unroll
    for (int i = 0; i < 2; ++i) {
      int hr = i * 32 + hrb;
      const bf16* s = A + (size_t)(m0 + hr) * K + ((size_t)ktc << 6) + ((c8 ^ (hr & 7)) << 3);
      gll16(s, &SA[buf][(i * 256 + tid) * 16]);
    }
  };
  auto stgB = [&](int buf, int ktc) {
#pragma unroll
    for (int i = 0; i < 4; ++i) {
      int hr = i * 32 + hrb;
      const bf16* s = BT + (size_t)(n0 + hr) * K + ((size_t)ktc << 6) + ((c8 ^ (hr & 7)) << 3);
      gll16(s, &SB[buf][(i * 256 + tid) * 16]);
    }
  };
  auto rdf = [&](const char* base, int rloc, int ks) -> bf16x8 {
    return *(const bf16x8*)(base + rloc * 128 + (((ks << 6) + (lg << 4)) ^ ((rloc & 7) << 4)));
  };

  f32x4 acc[2][4] = {};

  stgA(0, 0); stgB(0, 0);
  __syncthreads();
  for (int kt = 0; kt < nk; ++kt) {
    const int cur = kt & 1;
    if (kt + 1 < nk) { stgA(cur ^ 1, kt + 1); stgB(cur ^ 1, kt + 1); }
    bf16x8 af[2][2], bfr[4][2];
#pragma unroll
    for (int i = 0; i < 2; ++i)
#pragma unroll
      for (int ks = 0; ks < 2; ++ks)
        af[i][ks] = rdf(SA[cur], wr * 32 + i * 16 + lr, ks);
#pragma unroll
    for (int j = 0; j < 4; ++j)
#pragma unroll
      for (int ks = 0; ks < 2; ++ks)
        bfr[j][ks] = rdf(SB[cur], wc * 64 + j * 16 + lr, ks);
#pragma unroll
    for (int i = 0; i < 2; ++i)
#pragma unroll
      for (int j = 0; j < 4; ++j)
#pragma unroll
        for (int ks = 0; ks < 2; ++ks)
          acc[i][j] = mfma16(af[i][ks], bfr[j][ks], acc[i][j]);
    __syncthreads();
  }

  float* of = (float*)Cout;
  bf16*  ob = (bf16*)Cout;
#pragma unroll
  for (int j = 0; j < 4; ++j) {
    int gn = n0 + wc * 64 + j * 16 + lr;
    float bv = bias[gn];
#pragma unroll
    for (int i = 0; i < 2; ++i) {
      int gmb = m0 + wr * 32 + i * 16 + lg * 4;
#pragma unroll
      for (int rr = 0; rr < 4; ++rr) {
        size_t idx = (size_t)(gmb + rr) * N + gn;
        float v = acc[i][j][rr] + bv;
        if (EPI == 0) ob[idx] = (bf16)v;
        else if (EPI == 1) of[idx] += v;
        else {
          float ge = 0.5f * v * (1.f + erff(v * 0.70710678f));
          ob[idx] = (bf16)ge;
        }
      }
    }
  }
}

// ---------------- GEMM 256x256 8-phase counted-vmcnt (T2+T3+T4+T5) ----------------
template <int EPI>
__global__ __launch_bounds__(512, 2)
void k_gemm8(const bf16* __restrict__ A, const bf16* __restrict__ BT,
             const float* __restrict__ bias, void* __restrict__ Cout,
             int M, int N, int K) {
  __shared__ __align__(16) char SA[2][2][16384];
  __shared__ __align__(16) char SB[2][2][16384];
  const int tid = threadIdx.x;
  const int lane = tid & 63;
  const int w = tid >> 6;
  const int wm = w >> 2, wn = w & 3;
  const int lr = lane & 15, lg = lane >> 4;
  const int nk = K >> 6;

  const int nwg = gridDim.x;
  const int q = nwg >> 3, r = nwg & 7;
  const int xcd = blockIdx.x & 7, loc = blockIdx.x >> 3;
  const int wg = (xcd < r ? xcd * (q + 1) : r * (q + 1) + (xcd - r) * q) + loc;
  const int gy = M >> 8;
  const int m0 = (wg % gy) << 8, n0 = (wg / gy) << 8;

  const int c8 = tid & 7;
  auto stg = [&](char* dst, const bf16* src0, int base0, int half, int ktc) {
#pragma unroll
    for (int i = 0; i < 2; ++i) {
      int hr = i * 64 + (tid >> 3);
      const bf16* s = src0 + (size_t)(base0 + half * 128 + hr) * K + ((size_t)ktc << 6)
                    + ((c8 ^ (hr & 7)) << 3);
      gll16(s, dst + (i * 512 + tid) * 16);
    }
  };
  auto rdf = [&](const char* hbase, int rloc, int ks) -> bf16x8 {
    return *(const bf16x8*)(hbase + rloc * 128 + (((ks << 6) + (lg << 4)) ^ ((rloc & 7) << 4)));
  };

  f32x4 acc[8][4] = {};
  bf16x8 af[4][2], b0f[2][2], b1f[2][2];

  stg(SA[0][0], A, m0, 0, 0);
  stg(SB[0][0], BT, n0, 0, 0);
  stg(SB[0][1], BT, n0, 1, 0);
  stg(SA[0][1], A, m0, 1, 0);
  stg(SA[1][0], A, m0, 0, 1);
  stg(SB[1][0], BT, n0, 0, 1);
  asm volatile("s_waitcnt vmcnt(8)" ::: "memory");
  __builtin_amdgcn_s_barrier();

  for (int kt = 0; kt < nk; ++kt) {
    const int cur = kt & 1;
    const char* hA0 = SA[cur][0]; const char* hA1 = SA[cur][1];
    const char* hB0 = SB[cur][0]; const char* hB1 = SB[cur][1];
    const int tn  = (kt + 1 < nk) ? kt + 1 : nk - 1;
    const int tn2 = (kt + 2 < nk) ? kt + 2 : nk - 1;

    stg(SB[(kt + 1) & 1][1], BT, n0, 1, tn);
    asm volatile("s_waitcnt vmcnt(8)" ::: "memory");
#pragma unroll
    for (int i = 0; i < 4; ++i) {
      int rl = i * 32 + wm * 16 + lr;
#pragma unroll
      for (int ks = 0; ks < 2; ++ks) af[i][ks] = rdf(hA0, rl, ks);
    }
#pragma unroll
    for (int j = 0; j < 2; ++j) {
      int rl = j * 64 + wn * 16 + lr;
#pragma unroll
      for (int ks = 0; ks < 2; ++ks) b0f[j][ks] = rdf(hB0, rl, ks);
    }
    __builtin_amdgcn_s_barrier();
    __builtin_amdgcn_s_setprio(1);
#pragma unroll
    for (int i = 0; i < 4; ++i)
#pragma unroll
      for (int j = 0; j < 2; ++j)
#pragma unroll
        for (int ks = 0; ks < 2; ++ks)
          acc[i][j] = mfma16(af[i][ks], b0f[j][ks], acc[i][j]);
    __builtin_amdgcn_s_setprio(0);

    stg(SA[(kt + 1) & 1][1], A, m0, 1, tn);
    asm volatile("s_waitcnt vmcnt(8)" ::: "memory");
#pragma unroll
    for (int j = 0; j < 2; ++j) {
      int rl = j * 64 + wn * 16 + lr;
#pragma unroll
      for (int ks = 0; ks < 2; ++ks) b1f[j][ks] = rdf(hB1, rl, ks);
    }
    __builtin_amdgcn_s_barrier();
    __builtin_amdgcn_s_setprio(1);
#pragma unroll
    for (int i = 0; i < 4; ++i)
#pragma unroll
      for (int j = 0; j < 2; ++j)
#pragma unroll
        for (int ks = 0; ks < 2; ++ks)
          acc[i][2 + j] = mfma16(af[i][ks], b1f[j][ks], acc[i][2 + j]);
    __builtin_amdgcn_s_setprio(0);

    stg(SA[cur][0], A, m0, 0, tn2);
#pragma unroll
    for (int i = 0; i < 4; ++i) {
      int rl = i * 32 + wm * 16 + lr;
#pragma unroll
      for (int ks = 0; ks < 2; ++ks) af[i][ks] = rdf(hA1, rl, ks);
    }
    __builtin_amdgcn_s_barrier();
    __builtin_amdgcn_s_setprio(1);
#pragma unroll
    for (int i = 0; i < 4; ++i)
#pragma unroll
      for (int j = 0; j < 2; ++j)
#pragma unroll
        for (int ks = 0; ks < 2; ++ks)
          acc[4 + i][j] = mfma16(af[i][ks], b0f[j][ks], acc[4 + i][j]);
    __builtin_amdgcn_s_setprio(0);

    stg(SB[cur][0], BT, n0, 0, tn2);
    asm volatile("s_waitcnt vmcnt(8)" ::: "memory");
    __builtin_amdgcn_s_barrier();
    __builtin_amdgcn_s_setprio(1);
#pragma unroll
    for (int i = 0; i < 4; ++i)
#pragma unroll
      for (int j = 0; j < 2; ++j)
#pragma unroll
        for (int ks = 0; ks < 2; ++ks)
          acc[4 + i][2 + j] = mfma16(af[i][ks], b1f[j][ks], acc[4 + i][2 + j]);
    __builtin_amdgcn_s_setprio(0);
  }

  float* of = (float*)Cout;
  bf16*  ob = (bf16*)Cout;
#pragma unroll
  for (int ni = 0; ni < 4; ++ni) {
    int gn = n0 + (ni >> 1) * 128 + (ni & 1) * 64 + wn * 16 + lr;
    float bv = bias[gn];
#pragma unroll
    for (int mi = 0; mi < 8; ++mi) {
      int gmb = m0 + (mi >> 2) * 128 + (mi & 3) * 32 + wm * 16 + lg * 4;
#pragma unroll
      for (int rr = 0; rr < 4; ++rr) {
        size_t idx = (size_t)(gmb + rr) * N + gn;
        float v = acc[mi][ni][rr] + bv;
        if (EPI == 0) ob[idx] = (bf16)v;
        else if (EPI == 1) of[idx] += v;
        else {
          float ge = 0.5f * v * (1.f + erff(v * 0.70710678f));
          ob[idx] = (bf16)ge;
        }
      }
    }
  }
}

// ---------------- fused flash attention v4: LDS-free streaming (D=64, H=16) ----------------
// One wave = 16 q rows, fully independent (no barriers, no LDS). K fragments are
// MFMA-loaded straight from global (L2-resident, hb-pinned to XCD via id%8); V is
// read from pre-transposed VT[hb][64][Tkv] with the SAME k-slot permutation as pa
// (slots {lg*4+j, 16+lg*4+j} per 32-kv step) so the PV contraction is exact.
// kv-step 32; K register ping-pong prefetch (static indexing); causal mask only
// on the last step; lsum via ones-MFMA; exp2 with folded scale; defer-max THR=11.
template <bool CAUSAL>
__global__ __launch_bounds__(256)
void k_attn4(const bf16* __restrict__ Qb, int ldq,
             const bf16* __restrict__ Kb, int ldk, int kcol0,
             const bf16* __restrict__ VT, int Tkv,
             int qlen, bf16* __restrict__ Ob, int ldo, float sc2) {
  const int tid = threadIdx.x;
  const int lane = tid & 63;
  const int w = tid >> 6;
  const int lr = lane & 15, lg = lane >> 4;

  const int id = blockIdx.x;
  const int hb = ((id >> 8) << 3) | (id & 7);   // %8-pinned: all blocks of one hb share an XCD
  const int qg = (id >> 3) & 31;
  const int b = hb >> 4, h = hb & 15;
  const int qt = qg * 4 + w;
  const int q0 = qt * 16;
  const int nst = CAUSAL ? ((16 * qt + 47) >> 5) : (Tkv >> 5);

  // Q fragments (B-operand): lane holds q = q0+lr, d = kk*32 + lg*8 ..+8
  bf16x8 qf[2];
#pragma unroll
  for (int kk = 0; kk < 2; ++kk)
    qf[kk] = *(const bf16x8*)(Qb + (size_t)(b * qlen + q0 + lr) * ldq + h * 64 + kk * 32 + lg * 8);

  const bf16* Kbase = Kb + (size_t)b * Tkv * ldk + kcol0 + h * 64 + lg * 8;
  const bf16* Vslab = VT + (size_t)hb * 64 * Tkv + lg * 4;

  f32x4 o[4] = {};
  f32x4 ls = {};
  float mrun = -3.0e38f;

  bf16x8 ones;
#pragma unroll
  for (int i = 0; i < 8; ++i) ones[i] = (bf16)1.0f;

  auto loadK = [&](int st, bf16x8 (&kf)[4]) {
#pragma unroll
    for (int sub = 0; sub < 2; ++sub)
#pragma unroll
      for (int kk = 0; kk < 2; ++kk)
        kf[sub * 2 + kk] = *(const bf16x8*)(Kbase + (size_t)(st * 32 + sub * 16 + lr) * ldk + kk * 32);
  };

  auto step = [&](int st, const bf16x8 (&kf)[4]) {
    // V loads issued first (latency hides under QK + softmax)
    bf16x4 vlo[4], vhi[4];
#pragma unroll
    for (int dt = 0; dt < 4; ++dt) {
      const bf16* vp = Vslab + (size_t)(dt * 16 + lr) * Tkv + st * 32;
      vlo[dt] = *(const bf16x4*)vp;
      vhi[dt] = *(const bf16x4*)(vp + 16);
    }
    // QK^T (swapped): s[sub]: q = lr, kv = st*32 + sub*16 + lg*4 + j
    f32x4 s0 = {}, s1 = {};
    s0 = mfma16(kf[0], qf[0], s0);
    s0 = mfma16(kf[1], qf[1], s0);
    s1 = mfma16(kf[2], qf[0], s1);
    s1 = mfma16(kf[3], qf[1], s1);

    float v[8];
    float pmax = -3.0e38f;
    const bool dm = CAUSAL && (st == nst - 1);
    const int qg2 = q0 + lr;
#pragma unroll
    for (int i = 0; i < 8; ++i) {
      float x = (i < 4 ? s0[i] : s1[i - 4]) * sc2;
      if (dm) {
        int kvg = st * 32 + (i >> 2) * 16 + lg * 4 + (i & 3);
        if (kvg > qg2) x = -1.0e30f;
      }
      v[i] = x;
      pmax = fmaxf(pmax, x);
    }
    pmax = fmaxf(pmax, __shfl_xor(pmax, 16, 64));
    pmax = fmaxf(pmax, __shfl_xor(pmax, 32, 64));
    float m = mrun;
    if (__any(pmax - m > 11.f)) {
      float mnew = fmaxf(m, pmax);
      float alpha = exp2f(m - mnew);
      float al[4];
#pragma unroll
      for (int j = 0; j < 4; ++j) {
        int src = (lane & 48) | (lg * 4 + j);
        al[j] = __int_as_float(__builtin_amdgcn_ds_bpermute(src << 2, __float_as_int(alpha)));
      }
#pragma unroll
      for (int dt = 0; dt < 4; ++dt)
#pragma unroll
        for (int j = 0; j < 4; ++j) o[dt][j] *= al[j];
#pragma unroll
      for (int j = 0; j < 4; ++j) ls[j] *= al[j];
      mrun = mnew;
      m = mnew;
    }
    bf16x8 pa;
#pragma unroll
    for (int i = 0; i < 4; ++i) {
      pa[i]     = (bf16)exp2f(v[i] - m);
      pa[4 + i] = (bf16)exp2f(v[4 + i] - m);
    }
    // PV: vf k-slots match pa's (kv = {lg*4+j, 16+lg*4+j})
#pragma unroll
    for (int dt = 0; dt < 4; ++dt) {
      bf16x8 vf = __builtin_shufflevector(vlo[dt], vhi[dt], 0, 1, 2, 3, 4, 5, 6, 7);
      o[dt] = mfma16(pa, vf, o[dt]);
    }
    ls = mfma16(pa, ones, ls);
  };

  bf16x8 kfA[4], kfB[4];
  loadK(0, kfA);
  int st = 0;
  while (true) {
    if (st + 1 < nst) loadK(st + 1, kfB);
    step(st, kfA);
    ++st; if (st >= nst) break;
    if (st + 1 < nst) loadK(st + 1, kfA);
    step(st, kfB);
    ++st; if (st >= nst) break;
  }

  // finalize: ls already in O's (q,d) lane layout
#pragma unroll
  for (int dt = 0; dt < 4; ++dt)
#pragma unroll
    for (int j = 0; j < 4; ++j) {
      int gq = b * qlen + q0 + lg * 4 + j;
      Ob[(size_t)gq * ldo + h * 64 + dt * 16 + lr] = (bf16)(o[dt][j] / ls[j]);
    }
}

// ---------------- host orchestration ----------------
extern "C" void kernel_launch(void* const* d_in, const int* in_sizes, int n_in,
                              void* d_out, int out_size, void* d_ws, size_t ws_size,
                              hipStream_t stream) {
  (void)in_sizes; (void)n_in; (void)out_size; (void)ws_size;
  const float* x        = (const float*)d_in[0];
  const float* plan     = (const float*)d_in[1];
  const float* ln1_g    = (const float*)d_in[2];
  const float* ln1_b    = (const float*)d_in[3];
  const float* c_attn_w = (const float*)d_in[4];
  const float* c_attn_b = (const float*)d_in[5];
  const float* aproj_w  = (const float*)d_in[6];
  const float* aproj_b  = (const float*)d_in[7];
  const float* ln2_g    = (const float*)d_in[8];
  const float* ln2_b    = (const float*)d_in[9];
  const float* q_w      = (const float*)d_in[10];
  const float* q_b      = (const float*)d_in[11];
  const float* k_w      = (const float*)d_in[12];
  const float* k_b      = (const float*)d_in[13];
  const float* v_w      = (const float*)d_in[14];
  const float* v_b      = (const float*)d_in[15];
  const float* ca_w     = (const float*)d_in[16];
  const float* ca_b     = (const float*)d_in[17];
  const float* ln3_g    = (const float*)d_in[18];
  const float* ln3_b    = (const float*)d_in[19];
  const float* fc_w     = (const float*)d_in[20];
  const float* fc_b     = (const float*)d_in[21];
  const float* mp_w     = (const float*)d_in[22];
  const float* mp_b     = (const float*)d_in[23];

  char* ws = (char*)d_ws;
  bf16*  wbuf   = (bf16*)(ws);                        // 8 MiB rotating W^T
  bf16*  lnb    = (bf16*)(ws + (8ull << 20));         // 8 MiB LN output
  bf16*  planb  = (bf16*)(ws + (16ull << 20));        // 2 MiB plan bf16
  bf16*  yb     = (bf16*)(ws + (18ull << 20));        // 8 MiB attn output
  char*  rega   = ws + (26ull << 20);                 // 32 MiB region (qkv+vts | qx+kv+vtx | hmid)
  float* biaskv = (float*)(ws + (58ull << 20));       // 8 KiB
  bf16* qkv  = (bf16*)rega;                           // 24 MiB
  bf16* vts  = (bf16*)(rega + (24ull << 20));         // 8 MiB V^T self [32][64][2048]
  bf16* qx   = (bf16*)rega;                           // 8 MiB
  bf16* kvc  = (bf16*)(rega + (8ull << 20));          // 4 MiB
  bf16* vtx  = (bf16*)(rega + (12ull << 20));         // 2 MiB V^T cross [32][64][512]
  bf16* hmid = (bf16*)rega;                           // 32 MiB
  float* xw = (float*)d_out;   // running residual stream (fp32)

  const float SC2 = 0.125f * 1.4426950408889634f;  // scale * log2(e)
  dim3 wtb(32, 8);

  k_copy_f32<<<4096, 256, 0, stream>>>(x, xw, 1048576);
  k_conv_bf16<<<1024, 256, 0, stream>>>(plan, planb, 262144);
  k_concat2<<<8, 256, 0, stream>>>(k_b, v_b, biaskv, 1024);

  // ----- self-attention -----
  k_ln<<<4096, 256, 0, stream>>>(xw, ln1_g, ln1_b, lnb);
  k_wt<<<dim3(96, 32), wtb, 0, stream>>>(c_attn_w, wbuf, 1024, 3072);
  k_gemm8<0><<<192, 512, 0, stream>>>(lnb, wbuf, c_attn_b, qkv, 4096, 3072, 1024);
  k_vt<<<dim3(64, 2, 32), wtb, 0, stream>>>(qkv, 3072, 2048, 2048, vts);
  k_attn4<true><<<1024, 256, 0, stream>>>(qkv, 3072, qkv, 3072, 1024, vts, 2048,
                                          2048, yb, 1024, SC2);
  k_wt<<<dim3(32, 32), wtb, 0, stream>>>(aproj_w, wbuf, 1024, 1024);
  k_gemm_s<1><<<512, 256, 0, stream>>>(yb, wbuf, aproj_b, xw, 4096, 1024, 1024);

  // ----- cross-attention -----
  k_ln<<<4096, 256, 0, stream>>>(xw, ln2_g, ln2_b, lnb);
  k_wt<<<dim3(32, 32), wtb, 0, stream>>>(q_w, wbuf, 1024, 1024);
  k_gemm_s<0><<<512, 256, 0, stream>>>(lnb, wbuf, q_b, qx, 4096, 1024, 1024);
  k_wt<<<dim3(32, 32), wtb, 0, stream>>>(k_w, wbuf, 1024, 1024);
  k_wt<<<dim3(32, 32), wtb, 0, stream>>>(v_w, wbuf + 1024 * 1024, 1024, 1024);
  k_gemm_s<0><<<256, 256, 0, stream>>>(planb, wbuf, biaskv, kvc, 1024, 2048, 1024);
  k_vt<<<dim3(16, 2, 32), wtb, 0, stream>>>(kvc, 2048, 1024, 512, vtx);
  k_attn4<false><<<1024, 256, 0, stream>>>(qx, 1024, kvc, 2048, 0, vtx, 512,
                                           2048, yb, 1024, SC2);
  k_wt<<<dim3(32, 32), wtb, 0, stream>>>(ca_w, wbuf, 1024, 1024);
  k_gemm_s<1><<<512, 256, 0, stream>>>(yb, wbuf, ca_b, xw, 4096, 1024, 1024);

  // ----- MLP -----
  k_ln<<<4096, 256, 0, stream>>>(xw, ln3_g, ln3_b, lnb);
  k_wt<<<dim3(128, 32), wtb, 0, stream>>>(fc_w, wbuf, 1024, 4096);
  k_gemm8<2><<<256, 512, 0, stream>>>(lnb, wbuf, fc_b, hmid, 4096, 4096, 1024);
  k_wt<<<dim3(32, 128), wtb, 0, stream>>>(mp_w, wbuf, 4096, 1024);
  k_gemm_s<1><<<512, 256, 0, stream>>>(hmid, wbuf, mp_b, xw, 4096, 1024, 4096);
}

// Round 7
// 394.707 us; speedup vs baseline: 1.6434x; 1.6434x over previous
//
#include <hip/hip_runtime.h>
#include <stdint.h>

typedef __bf16 bf16;
typedef __bf16 bf16x4 __attribute__((ext_vector_type(4)));
typedef __bf16 bf16x8 __attribute__((ext_vector_type(8)));
typedef float  f32x4  __attribute__((ext_vector_type(4)));

#define DEVI __device__ __forceinline__

DEVI void gll16(const void* g, void* l) {
  __builtin_amdgcn_global_load_lds(
      (const __attribute__((address_space(1))) void*)g,
      (__attribute__((address_space(3))) void*)l,
      16, 0, 0);
}

DEVI f32x4 mfma16(bf16x8 a, bf16x8 b, f32x4 c) {
  return __builtin_amdgcn_mfma_f32_16x16x32_bf16(a, b, c, 0, 0, 0);
}

// ---------------- elementwise ----------------
__global__ void k_copy_f32(const float* __restrict__ in, float* __restrict__ out, int n4) {
  int i = blockIdx.x * 256 + threadIdx.x;
  if (i < n4) ((f32x4*)out)[i] = ((const f32x4*)in)[i];
}

__global__ void k_conv_bf16(const float* __restrict__ in, bf16* __restrict__ out, int n4) {
  int i = blockIdx.x * 256 + threadIdx.x;
  if (i < n4) {
    f32x4 v = ((const f32x4*)in)[i];
    bf16x4 o;
    o[0] = (bf16)v[0]; o[1] = (bf16)v[1]; o[2] = (bf16)v[2]; o[3] = (bf16)v[3];
    ((bf16x4*)out)[i] = o;
  }
}

__global__ void k_concat2(const float* __restrict__ a, const float* __restrict__ b,
                          float* __restrict__ out, int n) {
  int i = blockIdx.x * 256 + threadIdx.x;
  if (i < n) out[i] = a[i];
  else if (i < 2 * n) out[i] = b[i - n];
}

// ------------- weight fp32 [K][N] -> bf16 W^T [N][K] -------------
__global__ void k_wt(const float* __restrict__ W, bf16* __restrict__ WT, int K, int N) {
  __shared__ float t[32][33];
  int bn = blockIdx.x * 32, bk = blockIdx.y * 32;
  int tx = threadIdx.x, ty = threadIdx.y;
#pragma unroll
  for (int i = 0; i < 4; ++i)
    t[ty + i * 8][tx] = W[(size_t)(bk + ty + i * 8) * N + bn + tx];
  __syncthreads();
#pragma unroll
  for (int i = 0; i < 4; ++i)
    WT[(size_t)(bn + ty + i * 8) * K + bk + tx] = (bf16)t[tx][ty + i * 8];
}

// ---------------- layernorm (C=1024) fp32 -> bf16 ----------------
__global__ __launch_bounds__(256)
void k_ln(const float* __restrict__ x, const float* __restrict__ g,
          const float* __restrict__ b, bf16* __restrict__ out) {
  int row = blockIdx.x, tid = threadIdx.x;
  f32x4 v = ((const f32x4*)(x + (size_t)row * 1024))[tid];
  float s = v[0] + v[1] + v[2] + v[3];
  float sq = v[0]*v[0] + v[1]*v[1] + v[2]*v[2] + v[3]*v[3];
#pragma unroll
  for (int m = 1; m < 64; m <<= 1) {
    s  += __shfl_xor(s, m, 64);
    sq += __shfl_xor(sq, m, 64);
  }
  __shared__ float ps[4], psq[4];
  int w = tid >> 6;
  if ((tid & 63) == 0) { ps[w] = s; psq[w] = sq; }
  __syncthreads();
  s  = ps[0] + ps[1] + ps[2] + ps[3];
  sq = psq[0] + psq[1] + psq[2] + psq[3];
  float mean = s * (1.f / 1024.f);
  float rs = rsqrtf(sq * (1.f / 1024.f) - mean * mean + 1e-5f);
  f32x4 gv = ((const f32x4*)g)[tid];
  f32x4 bv = ((const f32x4*)b)[tid];
  bf16x4 o;
#pragma unroll
  for (int i = 0; i < 4; ++i) o[i] = (bf16)((v[i] - mean) * rs * gv[i] + bv[i]);
  ((bf16x4*)(out + (size_t)row * 1024))[tid] = o;
}

// ---------------- GEMM small-tile: BM=64 BN=128 BK=64, 2-phase, 3 blk/CU ----------------
template <int EPI>
__global__ __launch_bounds__(256, 3)
void k_gemm_s(const bf16* __restrict__ A, const bf16* __restrict__ BT,
              const float* __restrict__ bias, void* __restrict__ Cout,
              int M, int N, int K) {
  __shared__ __align__(16) char SA[2][8192];
  __shared__ __align__(16) char SB[2][16384];
  const int tid = threadIdx.x;
  const int lane = tid & 63;
  const int w = tid >> 6;
  const int wr = w >> 1, wc = w & 1;
  const int lr = lane & 15, lg = lane >> 4;
  const int nk = K >> 6;

  const int nwg = gridDim.x;
  const int q = nwg >> 3, r = nwg & 7;
  const int xcd = blockIdx.x & 7, loc = blockIdx.x >> 3;
  const int wg = (xcd < r ? xcd * (q + 1) : r * (q + 1) + (xcd - r) * q) + loc;
  const int gy = M >> 6;
  const int m0 = (wg % gy) << 6, n0 = (wg / gy) << 7;

  const int c8 = tid & 7;
  const int hrb = tid >> 3;
  auto stgA = [&](int buf, int ktc) {
#pragma unroll
    for (int i = 0; i < 2; ++i) {
      int hr = i * 32 + hrb;
      const bf16* s = A + (size_t)(m0 + hr) * K + ((size_t)ktc << 6) + ((c8 ^ (hr & 7)) << 3);
      gll16(s, &SA[buf][(i * 256 + tid) * 16]);
    }
  };
  auto stgB = [&](int buf, int ktc) {
#pragma unroll
    for (int i = 0; i < 4; ++i) {
      int hr = i * 32 + hrb;
      const bf16* s = BT + (size_t)(n0 + hr) * K + ((size_t)ktc << 6) + ((c8 ^ (hr & 7)) << 3);
      gll16(s, &SB[buf][(i * 256 + tid) * 16]);
    }
  };
  auto rdf = [&](const char* base, int rloc, int ks) -> bf16x8 {
    return *(const bf16x8*)(base + rloc * 128 + (((ks << 6) + (lg << 4)) ^ ((rloc & 7) << 4)));
  };

  f32x4 acc[2][4] = {};

  stgA(0, 0); stgB(0, 0);
  __syncthreads();
  for (int kt = 0; kt < nk; ++kt) {
    const int cur = kt & 1;
    if (kt + 1 < nk) { stgA(cur ^ 1, kt + 1); stgB(cur ^ 1, kt + 1); }
    bf16x8 af[2][2], bfr[4][2];
#pragma unroll
    for (int i = 0; i < 2; ++i)
#pragma unroll
      for (int ks = 0; ks < 2; ++ks)
        af[i][ks] = rdf(SA[cur], wr * 32 + i * 16 + lr, ks);
#pragma unroll
    for (int j = 0; j < 4; ++j)
#pragma unroll
      for (int ks = 0; ks < 2; ++ks)
        bfr[j][ks] = rdf(SB[cur], wc * 64 + j * 16 + lr, ks);
#pragma unroll
    for (int i = 0; i < 2; ++i)
#pragma unroll
      for (int j = 0; j < 4; ++j)
#pragma unroll
        for (int ks = 0; ks < 2; ++ks)
          acc[i][j] = mfma16(af[i][ks], bfr[j][ks], acc[i][j]);
    __syncthreads();
  }

  float* of = (float*)Cout;
  bf16*  ob = (bf16*)Cout;
#pragma unroll
  for (int j = 0; j < 4; ++j) {
    int gn = n0 + wc * 64 + j * 16 + lr;
    float bv = bias[gn];
#pragma unroll
    for (int i = 0; i < 2; ++i) {
      int gmb = m0 + wr * 32 + i * 16 + lg * 4;
#pragma unroll
      for (int rr = 0; rr < 4; ++rr) {
        size_t idx = (size_t)(gmb + rr) * N + gn;
        float v = acc[i][j][rr] + bv;
        if (EPI == 0) ob[idx] = (bf16)v;
        else if (EPI == 1) of[idx] += v;
        else {
          float ge = 0.5f * v * (1.f + erff(v * 0.70710678f));
          ob[idx] = (bf16)ge;
        }
      }
    }
  }
}

// ---------------- GEMM 256x256 8-phase counted-vmcnt (T2+T3+T4+T5) ----------------
template <int EPI>
__global__ __launch_bounds__(512, 2)
void k_gemm8(const bf16* __restrict__ A, const bf16* __restrict__ BT,
             const float* __restrict__ bias, void* __restrict__ Cout,
             int M, int N, int K) {
  __shared__ __align__(16) char SA[2][2][16384];
  __shared__ __align__(16) char SB[2][2][16384];
  const int tid = threadIdx.x;
  const int lane = tid & 63;
  const int w = tid >> 6;
  const int wm = w >> 2, wn = w & 3;
  const int lr = lane & 15, lg = lane >> 4;
  const int nk = K >> 6;

  const int nwg = gridDim.x;
  const int q = nwg >> 3, r = nwg & 7;
  const int xcd = blockIdx.x & 7, loc = blockIdx.x >> 3;
  const int wg = (xcd < r ? xcd * (q + 1) : r * (q + 1) + (xcd - r) * q) + loc;
  const int gy = M >> 8;
  const int m0 = (wg % gy) << 8, n0 = (wg / gy) << 8;

  const int c8 = tid & 7;
  auto stg = [&](char* dst, const bf16* src0, int base0, int half, int ktc) {
#pragma unroll
    for (int i = 0; i < 2; ++i) {
      int hr = i * 64 + (tid >> 3);
      const bf16* s = src0 + (size_t)(base0 + half * 128 + hr) * K + ((size_t)ktc << 6)
                    + ((c8 ^ (hr & 7)) << 3);
      gll16(s, dst + (i * 512 + tid) * 16);
    }
  };
  auto rdf = [&](const char* hbase, int rloc, int ks) -> bf16x8 {
    return *(const bf16x8*)(hbase + rloc * 128 + (((ks << 6) + (lg << 4)) ^ ((rloc & 7) << 4)));
  };

  f32x4 acc[8][4] = {};
  bf16x8 af[4][2], b0f[2][2], b1f[2][2];

  stg(SA[0][0], A, m0, 0, 0);
  stg(SB[0][0], BT, n0, 0, 0);
  stg(SB[0][1], BT, n0, 1, 0);
  stg(SA[0][1], A, m0, 1, 0);
  stg(SA[1][0], A, m0, 0, 1);
  stg(SB[1][0], BT, n0, 0, 1);
  asm volatile("s_waitcnt vmcnt(8)" ::: "memory");
  __builtin_amdgcn_s_barrier();

  for (int kt = 0; kt < nk; ++kt) {
    const int cur = kt & 1;
    const char* hA0 = SA[cur][0]; const char* hA1 = SA[cur][1];
    const char* hB0 = SB[cur][0]; const char* hB1 = SB[cur][1];
    const int tn  = (kt + 1 < nk) ? kt + 1 : nk - 1;
    const int tn2 = (kt + 2 < nk) ? kt + 2 : nk - 1;

    stg(SB[(kt + 1) & 1][1], BT, n0, 1, tn);
    asm volatile("s_waitcnt vmcnt(8)" ::: "memory");
#pragma unroll
    for (int i = 0; i < 4; ++i) {
      int rl = i * 32 + wm * 16 + lr;
#pragma unroll
      for (int ks = 0; ks < 2; ++ks) af[i][ks] = rdf(hA0, rl, ks);
    }
#pragma unroll
    for (int j = 0; j < 2; ++j) {
      int rl = j * 64 + wn * 16 + lr;
#pragma unroll
      for (int ks = 0; ks < 2; ++ks) b0f[j][ks] = rdf(hB0, rl, ks);
    }
    __builtin_amdgcn_s_barrier();
    __builtin_amdgcn_s_setprio(1);
#pragma unroll
    for (int i = 0; i < 4; ++i)
#pragma unroll
      for (int j = 0; j < 2; ++j)
#pragma unroll
        for (int ks = 0; ks < 2; ++ks)
          acc[i][j] = mfma16(af[i][ks], b0f[j][ks], acc[i][j]);
    __builtin_amdgcn_s_setprio(0);

    stg(SA[(kt + 1) & 1][1], A, m0, 1, tn);
    asm volatile("s_waitcnt vmcnt(8)" ::: "memory");
#pragma unroll
    for (int j = 0; j < 2; ++j) {
      int rl = j * 64 + wn * 16 + lr;
#pragma unroll
      for (int ks = 0; ks < 2; ++ks) b1f[j][ks] = rdf(hB1, rl, ks);
    }
    __builtin_amdgcn_s_barrier();
    __builtin_amdgcn_s_setprio(1);
#pragma unroll
    for (int i = 0; i < 4; ++i)
#pragma unroll
      for (int j = 0; j < 2; ++j)
#pragma unroll
        for (int ks = 0; ks < 2; ++ks)
          acc[i][2 + j] = mfma16(af[i][ks], b1f[j][ks], acc[i][2 + j]);
    __builtin_amdgcn_s_setprio(0);

    stg(SA[cur][0], A, m0, 0, tn2);
#pragma unroll
    for (int i = 0; i < 4; ++i) {
      int rl = i * 32 + wm * 16 + lr;
#pragma unroll
      for (int ks = 0; ks < 2; ++ks) af[i][ks] = rdf(hA1, rl, ks);
    }
    __builtin_amdgcn_s_barrier();
    __builtin_amdgcn_s_setprio(1);
#pragma unroll
    for (int i = 0; i < 4; ++i)
#pragma unroll
      for (int j = 0; j < 2; ++j)
#pragma unroll
        for (int ks = 0; ks < 2; ++ks)
          acc[4 + i][j] = mfma16(af[i][ks], b0f[j][ks], acc[4 + i][j]);
    __builtin_amdgcn_s_setprio(0);

    stg(SB[cur][0], BT, n0, 0, tn2);
    asm volatile("s_waitcnt vmcnt(8)" ::: "memory");
    __builtin_amdgcn_s_barrier();
    __builtin_amdgcn_s_setprio(1);
#pragma unroll
    for (int i = 0; i < 4; ++i)
#pragma unroll
      for (int j = 0; j < 2; ++j)
#pragma unroll
        for (int ks = 0; ks < 2; ++ks)
          acc[4 + i][2 + j] = mfma16(af[i][ks], b1f[j][ks], acc[4 + i][2 + j]);
    __builtin_amdgcn_s_setprio(0);
  }

  float* of = (float*)Cout;
  bf16*  ob = (bf16*)Cout;
#pragma unroll
  for (int ni = 0; ni < 4; ++ni) {
    int gn = n0 + (ni >> 1) * 128 + (ni & 1) * 64 + wn * 16 + lr;
    float bv = bias[gn];
#pragma unroll
    for (int mi = 0; mi < 8; ++mi) {
      int gmb = m0 + (mi >> 2) * 128 + (mi & 3) * 32 + wm * 16 + lg * 4;
#pragma unroll
      for (int rr = 0; rr < 4; ++rr) {
        size_t idx = (size_t)(gmb + rr) * N + gn;
        float v = acc[mi][ni][rr] + bv;
        if (EPI == 0) ob[idx] = (bf16)v;
        else if (EPI == 1) of[idx] += v;
        else {
          float ge = 0.5f * v * (1.f + erff(v * 0.70710678f));
          ob[idx] = (bf16)ge;
        }
      }
    }
  }
}

// ---------------- fused flash attention v5: split-KV (D=64, H=16) ----------------
// k_attn2 structure (QBLK=128, 4 waves, dbuf K gll16 + reg-staged V, 1 barrier/tile)
// + split-KV: grid (512 pairs, 2 splits); split s does kv tiles [s*half, (s+1)*half),
// half = nkv/2 (nkv always even). Partials (unnormalized o bf16, m/ls f32) merged
// by k_amerge. mrun init -1e30 vs mask -1e38 so fully-masked rows in split 1 give
// P=0 / merge weight 0 (NOT the exp2(m-m)=1 trap). lsum via ones-MFMA; exp2 with
// folded scale (sc2); defer-max THR=11 (log2 units).
template <bool CAUSAL>
__global__ __launch_bounds__(256)
void k_attn5(const bf16* __restrict__ Qb, int ldq,
             const bf16* __restrict__ Kb, int kcol0,
             const bf16* __restrict__ Vb, int vcol0,
             int ldkv, int qlen, int kvlen,
             bf16* __restrict__ po0, bf16* __restrict__ po1,
             float* __restrict__ pml, float sc2) {
  const int tid = threadIdx.x;
  const int lane = tid & 63;
  const int w = tid >> 6;
  const int lr = lane & 15, lg = lane >> 4;

  const int id = blockIdx.x;
  const int s = blockIdx.y;
  int h, b, qt;
  if (CAUSAL) {
    int low = id & 255;
    h = low & 15; b = (low >> 4) & 1;
    int q3 = low >> 5;
    qt = (id >> 8) ? (8 + q3) : (7 - q3);
  } else {
    h = id & 15; b = (id >> 4) & 1; qt = id >> 5;
  }

  const int qbase = qt * 128;
  const int kvbase = b * kvlen;
  const int nkv = CAUSAL ? (2 * qt + 2) : (kvlen >> 6);
  const int half = nkv >> 1;
  const int k0 = s * half, k1 = k0 + half;
  const int mask_from = CAUSAL ? (nkv - 2) : 0x7fffffff;

  bf16x8 qf[2][2];
#pragma unroll
  for (int g = 0; g < 2; ++g)
#pragma unroll
    for (int kk = 0; kk < 2; ++kk)
      qf[g][kk] = *(const bf16x8*)(Qb + (size_t)(b * qlen + qbase + w * 32 + g * 16 + lr) * ldq
                                   + h * 64 + kk * 32 + lg * 8);

  __shared__ __align__(16) char Klds[2][8192];
  __shared__ __align__(16) bf16 VT[2][64][68];

  f32x4 o[2][4] = {};
  f32x4 ls[2] = {};
  float mrun[2] = {-1.0e30f, -1.0e30f};

  bf16x8 ones;
#pragma unroll
  for (int i = 0; i < 8; ++i) ones[i] = (bf16)1.0f;

  bf16x8 vr0, vr1;
  const int vkv = lane;
  const int vd0 = (tid >> 6) * 16;
  const bf16* Vbase = Vb + vcol0 + h * 64 + vd0;

  auto stageK = [&](int buf, int kvt) {
#pragma unroll
    for (int t = 0; t < 2; ++t) {
      int r = t * 32 + (tid >> 3);
      int pb = (tid & 7) * 16;
      const char* gs = (const char*)(Kb + (size_t)(kvbase + kvt * 64 + r) * ldkv + kcol0 + h * 64)
                       + (pb ^ ((r & 7) << 4));
      gll16(gs, &Klds[buf][t * 4096 + tid * 16]);
    }
  };
  auto loadV = [&](int kvt) {
    const bf16* vp = Vbase + (size_t)(kvbase + kvt * 64 + vkv) * ldkv;
    vr0 = *(const bf16x8*)vp;
    vr1 = *(const bf16x8*)(vp + 8);
  };
  auto writeV = [&](int buf) {
#pragma unroll
    for (int i = 0; i < 8; ++i) VT[buf][vd0 + i][vkv] = vr0[i];
#pragma unroll
    for (int i = 0; i < 8; ++i) VT[buf][vd0 + 8 + i][vkv] = vr1[i];
  };

  stageK(0, k0);
  loadV(k0);
  writeV(0);
  __syncthreads();

  int cur = 0;
  for (int kvt = k0; kvt < k1; ++kvt) {
    if (kvt + 1 < k1) { stageK(cur ^ 1, kvt + 1); loadV(kvt + 1); }

    f32x4 sc[2][4] = {};
    __builtin_amdgcn_s_setprio(1);
#pragma unroll
    for (int sub = 0; sub < 4; ++sub) {
      int row = sub * 16 + lr;
#pragma unroll
      for (int kk = 0; kk < 2; ++kk) {
        bf16x8 kf = *(const bf16x8*)&Klds[cur][(row << 7) + ((kk * 64 + lg * 16) ^ ((row & 7) << 4))];
        sc[0][sub] = mfma16(kf, qf[0][kk], sc[0][sub]);
        sc[1][sub] = mfma16(kf, qf[1][kk], sc[1][sub]);
      }
    }
    __builtin_amdgcn_s_setprio(0);

    const bool domask = CAUSAL && (kvt >= mask_from);
    bf16x8 pa[2][2];
#pragma unroll
    for (int g = 0; g < 2; ++g) {
      const int qg = qbase + w * 32 + g * 16 + lr;
      float pmax = -1.0e38f;
#pragma unroll
      for (int sub = 0; sub < 4; ++sub)
#pragma unroll
        for (int j = 0; j < 4; ++j) {
          float v = sc[g][sub][j] * sc2;
          if (domask) {
            int kvg = kvt * 64 + sub * 16 + lg * 4 + j;
            if (kvg > qg) v = -1.0e38f;
          }
          sc[g][sub][j] = v;
          pmax = fmaxf(pmax, v);
        }
      pmax = fmaxf(pmax, __shfl_xor(pmax, 16, 64));
      pmax = fmaxf(pmax, __shfl_xor(pmax, 32, 64));
      float m = mrun[g];
      if (__any(pmax - m > 11.f)) {
        float mnew = fmaxf(m, pmax);
        float alpha = exp2f(m - mnew);
        float al[4];
#pragma unroll
        for (int j = 0; j < 4; ++j) {
          int src = (lane & 48) | (lg * 4 + j);
          al[j] = __int_as_float(__builtin_amdgcn_ds_bpermute(src << 2, __float_as_int(alpha)));
        }
#pragma unroll
        for (int dt = 0; dt < 4; ++dt)
#pragma unroll
          for (int j = 0; j < 4; ++j) o[g][dt][j] *= al[j];
#pragma unroll
        for (int j = 0; j < 4; ++j) ls[g][j] *= al[j];
        mrun[g] = mnew;
        m = mnew;
      }
#pragma unroll
      for (int sub = 0; sub < 4; ++sub)
#pragma unroll
        for (int j = 0; j < 4; ++j)
          sc[g][sub][j] = exp2f(sc[g][sub][j] - m);
#pragma unroll
      for (int sp = 0; sp < 2; ++sp)
#pragma unroll
        for (int j = 0; j < 4; ++j) {
          pa[g][sp][j]     = (bf16)sc[g][2 * sp][j];
          pa[g][sp][4 + j] = (bf16)sc[g][2 * sp + 1][j];
        }
    }

    bf16x8 vfr[2][4];
#pragma unroll
    for (int sp = 0; sp < 2; ++sp)
#pragma unroll
      for (int dt = 0; dt < 4; ++dt) {
        int d = dt * 16 + lr;
        bf16x4 va  = *(const bf16x4*)&VT[cur][d][sp * 32 + lg * 4];
        bf16x4 vb2 = *(const bf16x4*)&VT[cur][d][sp * 32 + 16 + lg * 4];
        vfr[sp][dt] = __builtin_shufflevector(va, vb2, 0, 1, 2, 3, 4, 5, 6, 7);
      }

    __builtin_amdgcn_s_setprio(1);
#pragma unroll
    for (int sp = 0; sp < 2; ++sp)
#pragma unroll
      for (int dt = 0; dt < 4; ++dt) {
        o[0][dt] = mfma16(pa[0][sp], vfr[sp][dt], o[0][dt]);
        o[1][dt] = mfma16(pa[1][sp], vfr[sp][dt], o[1][dt]);
      }
    ls[0] = mfma16(pa[0][0], ones, ls[0]);
    ls[0] = mfma16(pa[0][1], ones, ls[0]);
    ls[1] = mfma16(pa[1][0], ones, ls[1]);
    ls[1] = mfma16(pa[1][1], ones, ls[1]);
    __builtin_amdgcn_s_setprio(0);

    if (kvt + 1 < k1) writeV(cur ^ 1);
    __syncthreads();
    cur ^= 1;
  }

  // write partials: o unnormalized (bf16), m (q=lr layout) and ls (q=lg*4+j layout)
  bf16* po = s ? po1 : po0;
  const size_t pb = (size_t)id * 8192;
  float* ml = pml + (size_t)s * 131072 + (size_t)id * 256;
#pragma unroll
  for (int g = 0; g < 2; ++g) {
#pragma unroll
    for (int dt = 0; dt < 4; ++dt)
#pragma unroll
      for (int j = 0; j < 4; ++j) {
        int r = w * 32 + g * 16 + lg * 4 + j;
        po[pb + r * 64 + dt * 16 + lr] = (bf16)o[g][dt][j];
      }
    if (lg == 0) ml[(w * 32 + g * 16 + lr) * 2] = mrun[g];
    if (lr == 0)
#pragma unroll
      for (int j = 0; j < 4; ++j)
        ml[(w * 32 + g * 16 + lg * 4 + j) * 2 + 1] = ls[g][j];
  }
}

// ---------------- split-KV merge: out = (a0*o0 + a1*o1) / (a0*ls0 + a1*ls1) ----------------
template <bool CAUSAL>
__global__ __launch_bounds__(256)
void k_amerge(const bf16* __restrict__ po0, const bf16* __restrict__ po1,
              const float* __restrict__ pml, bf16* __restrict__ Ob,
              int qlen, int ldo) {
  const int id = blockIdx.x;
  int h, b, qt;
  if (CAUSAL) {
    int low = id & 255; h = low & 15; b = (low >> 4) & 1;
    int q3 = low >> 5;  qt = (id >> 8) ? (8 + q3) : (7 - q3);
  } else {
    h = id & 15; b = (id >> 4) & 1; qt = id >> 5;
  }
  const int t = threadIdx.x;
  const int r = t >> 1, hd = (t & 1) * 32;
  const float m0 = pml[(size_t)id * 256 + r * 2];
  const float l0 = pml[(size_t)id * 256 + r * 2 + 1];
  const float m1 = pml[131072 + (size_t)id * 256 + r * 2];
  const float l1 = pml[131072 + (size_t)id * 256 + r * 2 + 1];
  const float mm = fmaxf(m0, m1);
  const float a0 = exp2f(m0 - mm), a1 = exp2f(m1 - mm);
  const float inv = 1.0f / (a0 * l0 + a1 * l1);
  const size_t pbase = (size_t)id * 8192 + r * 64 + hd;
  bf16* orow = Ob + (size_t)(b * qlen + qt * 128 + r) * ldo + h * 64 + hd;
#pragma unroll
  for (int i = 0; i < 4; ++i) {
    bf16x8 v0 = *(const bf16x8*)(po0 + pbase + i * 8);
    bf16x8 v1 = *(const bf16x8*)(po1 + pbase + i * 8);
    bf16x8 ov;
#pragma unroll
    for (int e = 0; e < 8; ++e)
      ov[e] = (bf16)((a0 * (float)v0[e] + a1 * (float)v1[e]) * inv);
    *(bf16x8*)(orow + i * 8) = ov;
  }
}

// ---------------- host orchestration ----------------
extern "C" void kernel_launch(void* const* d_in, const int* in_sizes, int n_in,
                              void* d_out, int out_size, void* d_ws, size_t ws_size,
                              hipStream_t stream) {
  (void)in_sizes; (void)n_in; (void)out_size; (void)ws_size;
  const float* x        = (const float*)d_in[0];
  const float* plan     = (const float*)d_in[1];
  const float* ln1_g    = (const float*)d_in[2];
  const float* ln1_b    = (const float*)d_in[3];
  const float* c_attn_w = (const float*)d_in[4];
  const float* c_attn_b = (const float*)d_in[5];
  const float* aproj_w  = (const float*)d_in[6];
  const float* aproj_b  = (const float*)d_in[7];
  const float* ln2_g    = (const float*)d_in[8];
  const float* ln2_b    = (const float*)d_in[9];
  const float* q_w      = (const float*)d_in[10];
  const float* q_b      = (const float*)d_in[11];
  const float* k_w      = (const float*)d_in[12];
  const float* k_b      = (const float*)d_in[13];
  const float* v_w      = (const float*)d_in[14];
  const float* v_b      = (const float*)d_in[15];
  const float* ca_w     = (const float*)d_in[16];
  const float* ca_b     = (const float*)d_in[17];
  const float* ln3_g    = (const float*)d_in[18];
  const float* ln3_b    = (const float*)d_in[19];
  const float* fc_w     = (const float*)d_in[20];
  const float* fc_b     = (const float*)d_in[21];
  const float* mp_w     = (const float*)d_in[22];
  const float* mp_b     = (const float*)d_in[23];

  char* ws = (char*)d_ws;
  bf16*  wbuf   = (bf16*)(ws);                        // 8 MiB rotating W^T
  bf16*  lnb    = (bf16*)(ws + (8ull << 20));         // 8 MiB LN output (dead during attn)
  bf16*  planb  = (bf16*)(ws + (16ull << 20));        // 2 MiB plan bf16
  bf16*  yb     = (bf16*)(ws + (18ull << 20));        // 8 MiB attn output
  char*  rega   = ws + (26ull << 20);                 // 32 MiB region (qkv | qx+kv | hmid)
  float* biaskv = (float*)(ws + (58ull << 20));       // 8 KiB
  float* pml    = (float*)(ws + (58ull << 20) + (1ull << 20));  // 1 MiB [2][512][128][2]
  bf16* po0  = (bf16*)(ws + (8ull << 20));            // split-0 partials (aliases lnb; dead then)
  bf16* po1  = (bf16*)(ws + (50ull << 20));           // split-1 partials (rega tail, free)
  bf16* qkv  = (bf16*)rega;
  bf16* qx   = (bf16*)rega;
  bf16* kvc  = (bf16*)(rega + (8ull << 20));
  bf16* hmid = (bf16*)rega;
  float* xw = (float*)d_out;   // running residual stream (fp32)

  const float SC2 = 0.125f * 1.4426950408889634f;  // scale * log2(e)
  dim3 wtb(32, 8);

  k_copy_f32<<<4096, 256, 0, stream>>>(x, xw, 1048576);
  k_conv_bf16<<<1024, 256, 0, stream>>>(plan, planb, 262144);
  k_concat2<<<8, 256, 0, stream>>>(k_b, v_b, biaskv, 1024);

  // ----- self-attention -----
  k_ln<<<4096, 256, 0, stream>>>(xw, ln1_g, ln1_b, lnb);
  k_wt<<<dim3(96, 32), wtb, 0, stream>>>(c_attn_w, wbuf, 1024, 3072);
  k_gemm8<0><<<192, 512, 0, stream>>>(lnb, wbuf, c_attn_b, qkv, 4096, 3072, 1024);
  k_attn5<true><<<dim3(512, 2), 256, 0, stream>>>(qkv, 3072, qkv, 1024, qkv, 2048,
                                                  3072, 2048, 2048, po0, po1, pml, SC2);
  k_amerge<true><<<512, 256, 0, stream>>>(po0, po1, pml, yb, 2048, 1024);
  k_wt<<<dim3(32, 32), wtb, 0, stream>>>(aproj_w, wbuf, 1024, 1024);
  k_gemm_s<1><<<512, 256, 0, stream>>>(yb, wbuf, aproj_b, xw, 4096, 1024, 1024);

  // ----- cross-attention -----
  k_ln<<<4096, 256, 0, stream>>>(xw, ln2_g, ln2_b, lnb);
  k_wt<<<dim3(32, 32), wtb, 0, stream>>>(q_w, wbuf, 1024, 1024);
  k_gemm_s<0><<<512, 256, 0, stream>>>(lnb, wbuf, q_b, qx, 4096, 1024, 1024);
  k_wt<<<dim3(32, 32), wtb, 0, stream>>>(k_w, wbuf, 1024, 1024);
  k_wt<<<dim3(32, 32), wtb, 0, stream>>>(v_w, wbuf + 1024 * 1024, 1024, 1024);
  k_gemm_s<0><<<256, 256, 0, stream>>>(planb, wbuf, biaskv, kvc, 1024, 2048, 1024);
  k_attn5<false><<<dim3(512, 2), 256, 0, stream>>>(qx, 1024, kvc, 0, kvc, 1024,
                                                   2048, 2048, 512, po0, po1, pml, SC2);
  k_amerge<false><<<512, 256, 0, stream>>>(po0, po1, pml, yb, 2048, 1024);
  k_wt<<<dim3(32, 32), wtb, 0, stream>>>(ca_w, wbuf, 1024, 1024);
  k_gemm_s<1><<<512, 256, 0, stream>>>(yb, wbuf, ca_b, xw, 4096, 1024, 1024);

  // ----- MLP -----
  k_ln<<<4096, 256, 0, stream>>>(xw, ln3_g, ln3_b, lnb);
  k_wt<<<dim3(128, 32), wtb, 0, stream>>>(fc_w, wbuf, 1024, 4096);
  k_gemm8<2><<<256, 512, 0, stream>>>(lnb, wbuf, fc_b, hmid, 4096, 4096, 1024);
  k_wt<<<dim3(32, 128), wtb, 0, stream>>>(mp_w, wbuf, 4096, 1024);
  k_gemm_s<1><<<512, 256, 0, stream>>>(hmid, wbuf, mp_b, xw, 4096, 1024, 4096);
}

// Round 8
// 388.594 us; speedup vs baseline: 1.6693x; 1.0157x over previous
//
#include <hip/hip_runtime.h>
#include <stdint.h>

typedef __bf16 bf16;
typedef __bf16 bf16x4 __attribute__((ext_vector_type(4)));
typedef __bf16 bf16x8 __attribute__((ext_vector_type(8)));
typedef float  f32x4  __attribute__((ext_vector_type(4)));

#define DEVI __device__ __forceinline__

DEVI void gll16(const void* g, void* l) {
  __builtin_amdgcn_global_load_lds(
      (const __attribute__((address_space(1))) void*)g,
      (__attribute__((address_space(3))) void*)l,
      16, 0, 0);
}

DEVI f32x4 mfma16(bf16x8 a, bf16x8 b, f32x4 c) {
  return __builtin_amdgcn_mfma_f32_16x16x32_bf16(a, b, c, 0, 0, 0);
}

// ---------------- elementwise ----------------
__global__ void k_copy_f32(const float* __restrict__ in, float* __restrict__ out, int n4) {
  int i = blockIdx.x * 256 + threadIdx.x;
  if (i < n4) ((f32x4*)out)[i] = ((const f32x4*)in)[i];
}

__global__ void k_conv_bf16(const float* __restrict__ in, bf16* __restrict__ out, int n4) {
  int i = blockIdx.x * 256 + threadIdx.x;
  if (i < n4) {
    f32x4 v = ((const f32x4*)in)[i];
    bf16x4 o;
    o[0] = (bf16)v[0]; o[1] = (bf16)v[1]; o[2] = (bf16)v[2]; o[3] = (bf16)v[3];
    ((bf16x4*)out)[i] = o;
  }
}

__global__ void k_concat2(const float* __restrict__ a, const float* __restrict__ b,
                          float* __restrict__ out, int n) {
  int i = blockIdx.x * 256 + threadIdx.x;
  if (i < n) out[i] = a[i];
  else if (i < 2 * n) out[i] = b[i - n];
}

// ------------- weight fp32 [K][N] -> bf16 W^T [N][K] -------------
__global__ void k_wt(const float* __restrict__ W, bf16* __restrict__ WT, int K, int N) {
  __shared__ float t[32][33];
  int bn = blockIdx.x * 32, bk = blockIdx.y * 32;
  int tx = threadIdx.x, ty = threadIdx.y;
#pragma unroll
  for (int i = 0; i < 4; ++i)
    t[ty + i * 8][tx] = W[(size_t)(bk + ty + i * 8) * N + bn + tx];
  __syncthreads();
#pragma unroll
  for (int i = 0; i < 4; ++i)
    WT[(size_t)(bn + ty + i * 8) * K + bk + tx] = (bf16)t[tx][ty + i * 8];
}

// ------------- bf16 V-slab transpose: src rows b*Tlen+t, col colofs+h*64+d -> dst[hb][64][Tlen] -------------
__global__ void k_vt(const bf16* __restrict__ src, int ld, int colofs, int Tlen,
                     bf16* __restrict__ dst) {
  __shared__ bf16 t[32][33];
  int t0 = blockIdx.x * 32, d0 = blockIdx.y * 32, hb = blockIdx.z;
  int b = hb >> 4, h = hb & 15;
  int tx = threadIdx.x, ty = threadIdx.y;
  const bf16* s = src + (size_t)(b * Tlen + t0) * ld + colofs + h * 64 + d0;
#pragma unroll
  for (int i = 0; i < 4; ++i)
    t[ty + i * 8][tx] = s[(size_t)(ty + i * 8) * ld + tx];
  __syncthreads();
  bf16* o = dst + ((size_t)hb * 64 + d0) * Tlen + t0;
#pragma unroll
  for (int i = 0; i < 4; ++i)
    o[(size_t)(ty + i * 8) * Tlen + tx] = t[tx][ty + i * 8];
}

// ---------------- layernorm (C=1024) fp32 -> bf16 ----------------
__global__ __launch_bounds__(256)
void k_ln(const float* __restrict__ x, const float* __restrict__ g,
          const float* __restrict__ b, bf16* __restrict__ out) {
  int row = blockIdx.x, tid = threadIdx.x;
  f32x4 v = ((const f32x4*)(x + (size_t)row * 1024))[tid];
  float s = v[0] + v[1] + v[2] + v[3];
  float sq = v[0]*v[0] + v[1]*v[1] + v[2]*v[2] + v[3]*v[3];
#pragma unroll
  for (int m = 1; m < 64; m <<= 1) {
    s  += __shfl_xor(s, m, 64);
    sq += __shfl_xor(sq, m, 64);
  }
  __shared__ float ps[4], psq[4];
  int w = tid >> 6;
  if ((tid & 63) == 0) { ps[w] = s; psq[w] = sq; }
  __syncthreads();
  s  = ps[0] + ps[1] + ps[2] + ps[3];
  sq = psq[0] + psq[1] + psq[2] + psq[3];
  float mean = s * (1.f / 1024.f);
  float rs = rsqrtf(sq * (1.f / 1024.f) - mean * mean + 1e-5f);
  f32x4 gv = ((const f32x4*)g)[tid];
  f32x4 bv = ((const f32x4*)b)[tid];
  bf16x4 o;
#pragma unroll
  for (int i = 0; i < 4; ++i) o[i] = (bf16)((v[i] - mean) * rs * gv[i] + bv[i]);
  ((bf16x4*)(out + (size_t)row * 1024))[tid] = o;
}

// ---------------- GEMM small-tile: BM=64 BN=128 BK=64, 2-phase, 3 blk/CU ----------------
template <int EPI>
__global__ __launch_bounds__(256, 3)
void k_gemm_s(const bf16* __restrict__ A, const bf16* __restrict__ BT,
              const float* __restrict__ bias, void* __restrict__ Cout,
              int M, int N, int K) {
  __shared__ __align__(16) char SA[2][8192];
  __shared__ __align__(16) char SB[2][16384];
  const int tid = threadIdx.x;
  const int lane = tid & 63;
  const int w = tid >> 6;
  const int wr = w >> 1, wc = w & 1;
  const int lr = lane & 15, lg = lane >> 4;
  const int nk = K >> 6;

  const int nwg = gridDim.x;
  const int q = nwg >> 3, r = nwg & 7;
  const int xcd = blockIdx.x & 7, loc = blockIdx.x >> 3;
  const int wg = (xcd < r ? xcd * (q + 1) : r * (q + 1) + (xcd - r) * q) + loc;
  const int gy = M >> 6;
  const int m0 = (wg % gy) << 6, n0 = (wg / gy) << 7;

  const int c8 = tid & 7;
  const int hrb = tid >> 3;
  auto stgA = [&](int buf, int ktc) {
#pragma unroll
    for (int i = 0; i < 2; ++i) {
      int hr = i * 32 + hrb;
      const bf16* s = A + (size_t)(m0 + hr) * K + ((size_t)ktc << 6) + ((c8 ^ (hr & 7)) << 3);
      gll16(s, &SA[buf][(i * 256 + tid) * 16]);
    }
  };
  auto stgB = [&](int buf, int ktc) {
#pragma unroll
    for (int i = 0; i < 4; ++i) {
      int hr = i * 32 + hrb;
      const bf16* s = BT + (size_t)(n0 + hr) * K + ((size_t)ktc << 6) + ((c8 ^ (hr & 7)) << 3);
      gll16(s, &SB[buf][(i * 256 + tid) * 16]);
    }
  };
  auto rdf = [&](const char* base, int rloc, int ks) -> bf16x8 {
    return *(const bf16x8*)(base + rloc * 128 + (((ks << 6) + (lg << 4)) ^ ((rloc & 7) << 4)));
  };

  f32x4 acc[2][4] = {};

  stgA(0, 0); stgB(0, 0);
  __syncthreads();
  for (int kt = 0; kt < nk; ++kt) {
    const int cur = kt & 1;
    if (kt + 1 < nk) { stgA(cur ^ 1, kt + 1); stgB(cur ^ 1, kt + 1); }
    bf16x8 af[2][2], bfr[4][2];
#pragma unroll
    for (int i = 0; i < 2; ++i)
#pragma unroll
      for (int ks = 0; ks < 2; ++ks)
        af[i][ks] = rdf(SA[cur], wr * 32 + i * 16 + lr, ks);
#pragma unroll
    for (int j = 0; j < 4; ++j)
#pragma unroll
      for (int ks = 0; ks < 2; ++ks)
        bfr[j][ks] = rdf(SB[cur], wc * 64 + j * 16 + lr, ks);
#pragma unroll
    for (int i = 0; i < 2; ++i)
#pragma unroll
      for (int j = 0; j < 4; ++j)
#pragma unroll
        for (int ks = 0; ks < 2; ++ks)
          acc[i][j] = mfma16(af[i][ks], bfr[j][ks], acc[i][j]);
    __syncthreads();
  }

  float* of = (float*)Cout;
  bf16*  ob = (bf16*)Cout;
#pragma unroll
  for (int j = 0; j < 4; ++j) {
    int gn = n0 + wc * 64 + j * 16 + lr;
    float bv = bias[gn];
#pragma unroll
    for (int i = 0; i < 2; ++i) {
      int gmb = m0 + wr * 32 + i * 16 + lg * 4;
#pragma unroll
      for (int rr = 0; rr < 4; ++rr) {
        size_t idx = (size_t)(gmb + rr) * N + gn;
        float v = acc[i][j][rr] + bv;
        if (EPI == 0) ob[idx] = (bf16)v;
        else if (EPI == 1) of[idx] += v;
        else {
          float ge = 0.5f * v * (1.f + erff(v * 0.70710678f));
          ob[idx] = (bf16)ge;
        }
      }
    }
  }
}

// ---------------- GEMM 256x256 8-phase counted-vmcnt (T2+T3+T4+T5) ----------------
template <int EPI>
__global__ __launch_bounds__(512, 2)
void k_gemm8(const bf16* __restrict__ A, const bf16* __restrict__ BT,
             const float* __restrict__ bias, void* __restrict__ Cout,
             int M, int N, int K) {
  __shared__ __align__(16) char SA[2][2][16384];
  __shared__ __align__(16) char SB[2][2][16384];
  const int tid = threadIdx.x;
  const int lane = tid & 63;
  const int w = tid >> 6;
  const int wm = w >> 2, wn = w & 3;
  const int lr = lane & 15, lg = lane >> 4;
  const int nk = K >> 6;

  const int nwg = gridDim.x;
  const int q = nwg >> 3, r = nwg & 7;
  const int xcd = blockIdx.x & 7, loc = blockIdx.x >> 3;
  const int wg = (xcd < r ? xcd * (q + 1) : r * (q + 1) + (xcd - r) * q) + loc;
  const int gy = M >> 8;
  const int m0 = (wg % gy) << 8, n0 = (wg / gy) << 8;

  const int c8 = tid & 7;
  auto stg = [&](char* dst, const bf16* src0, int base0, int half, int ktc) {
#pragma unroll
    for (int i = 0; i < 2; ++i) {
      int hr = i * 64 + (tid >> 3);
      const bf16* s = src0 + (size_t)(base0 + half * 128 + hr) * K + ((size_t)ktc << 6)
                    + ((c8 ^ (hr & 7)) << 3);
      gll16(s, dst + (i * 512 + tid) * 16);
    }
  };
  auto rdf = [&](const char* hbase, int rloc, int ks) -> bf16x8 {
    return *(const bf16x8*)(hbase + rloc * 128 + (((ks << 6) + (lg << 4)) ^ ((rloc & 7) << 4)));
  };

  f32x4 acc[8][4] = {};
  bf16x8 af[4][2], b0f[2][2], b1f[2][2];

  stg(SA[0][0], A, m0, 0, 0);
  stg(SB[0][0], BT, n0, 0, 0);
  stg(SB[0][1], BT, n0, 1, 0);
  stg(SA[0][1], A, m0, 1, 0);
  stg(SA[1][0], A, m0, 0, 1);
  stg(SB[1][0], BT, n0, 0, 1);
  asm volatile("s_waitcnt vmcnt(8)" ::: "memory");
  __builtin_amdgcn_s_barrier();

  for (int kt = 0; kt < nk; ++kt) {
    const int cur = kt & 1;
    const char* hA0 = SA[cur][0]; const char* hA1 = SA[cur][1];
    const char* hB0 = SB[cur][0]; const char* hB1 = SB[cur][1];
    const int tn  = (kt + 1 < nk) ? kt + 1 : nk - 1;
    const int tn2 = (kt + 2 < nk) ? kt + 2 : nk - 1;

    stg(SB[(kt + 1) & 1][1], BT, n0, 1, tn);
    asm volatile("s_waitcnt vmcnt(8)" ::: "memory");
#pragma unroll
    for (int i = 0; i < 4; ++i) {
      int rl = i * 32 + wm * 16 + lr;
#pragma unroll
      for (int ks = 0; ks < 2; ++ks) af[i][ks] = rdf(hA0, rl, ks);
    }
#pragma unroll
    for (int j = 0; j < 2; ++j) {
      int rl = j * 64 + wn * 16 + lr;
#pragma unroll
      for (int ks = 0; ks < 2; ++ks) b0f[j][ks] = rdf(hB0, rl, ks);
    }
    __builtin_amdgcn_s_barrier();
    __builtin_amdgcn_s_setprio(1);
#pragma unroll
    for (int i = 0; i < 4; ++i)
#pragma unroll
      for (int j = 0; j < 2; ++j)
#pragma unroll
        for (int ks = 0; ks < 2; ++ks)
          acc[i][j] = mfma16(af[i][ks], b0f[j][ks], acc[i][j]);
    __builtin_amdgcn_s_setprio(0);

    stg(SA[(kt + 1) & 1][1], A, m0, 1, tn);
    asm volatile("s_waitcnt vmcnt(8)" ::: "memory");
#pragma unroll
    for (int j = 0; j < 2; ++j) {
      int rl = j * 64 + wn * 16 + lr;
#pragma unroll
      for (int ks = 0; ks < 2; ++ks) b1f[j][ks] = rdf(hB1, rl, ks);
    }
    __builtin_amdgcn_s_barrier();
    __builtin_amdgcn_s_setprio(1);
#pragma unroll
    for (int i = 0; i < 4; ++i)
#pragma unroll
      for (int j = 0; j < 2; ++j)
#pragma unroll
        for (int ks = 0; ks < 2; ++ks)
          acc[i][2 + j] = mfma16(af[i][ks], b1f[j][ks], acc[i][2 + j]);
    __builtin_amdgcn_s_setprio(0);

    stg(SA[cur][0], A, m0, 0, tn2);
#pragma unroll
    for (int i = 0; i < 4; ++i) {
      int rl = i * 32 + wm * 16 + lr;
#pragma unroll
      for (int ks = 0; ks < 2; ++ks) af[i][ks] = rdf(hA1, rl, ks);
    }
    __builtin_amdgcn_s_barrier();
    __builtin_amdgcn_s_setprio(1);
#pragma unroll
    for (int i = 0; i < 4; ++i)
#pragma unroll
      for (int j = 0; j < 2; ++j)
#pragma unroll
        for (int ks = 0; ks < 2; ++ks)
          acc[4 + i][j] = mfma16(af[i][ks], b0f[j][ks], acc[4 + i][j]);
    __builtin_amdgcn_s_setprio(0);

    stg(SB[cur][0], BT, n0, 0, tn2);
    asm volatile("s_waitcnt vmcnt(8)" ::: "memory");
    __builtin_amdgcn_s_barrier();
    __builtin_amdgcn_s_setprio(1);
#pragma unroll
    for (int i = 0; i < 4; ++i)
#pragma unroll
      for (int j = 0; j < 2; ++j)
#pragma unroll
        for (int ks = 0; ks < 2; ++ks)
          acc[4 + i][2 + j] = mfma16(af[i][ks], b1f[j][ks], acc[4 + i][2 + j]);
    __builtin_amdgcn_s_setprio(0);
  }

  float* of = (float*)Cout;
  bf16*  ob = (bf16*)Cout;
#pragma unroll
  for (int ni = 0; ni < 4; ++ni) {
    int gn = n0 + (ni >> 1) * 128 + (ni & 1) * 64 + wn * 16 + lr;
    float bv = bias[gn];
#pragma unroll
    for (int mi = 0; mi < 8; ++mi) {
      int gmb = m0 + (mi >> 2) * 128 + (mi & 3) * 32 + wm * 16 + lg * 4;
#pragma unroll
      for (int rr = 0; rr < 4; ++rr) {
        size_t idx = (size_t)(gmb + rr) * N + gn;
        float v = acc[mi][ni][rr] + bv;
        if (EPI == 0) ob[idx] = (bf16)v;
        else if (EPI == 1) of[idx] += v;
        else {
          float ge = 0.5f * v * (1.f + erff(v * 0.70710678f));
          ob[idx] = (bf16)ge;
        }
      }
    }
  }
}

// ---------------- fused flash attention v6 (D=64, H=16) ----------------
// r4's k_attn2 structure (QBLK=128, 4 waves, dbuf, 1 barrier/tile, pairing swizzle)
// with per-tile cost cuts:
//  - V^T pre-transposed in global (k_vt); V staged via gll16 like K (async DMA,
//    XOR-swizzled source) — deletes per-thread loadV/writeV (32 scalar ds_writes).
//  - lsum via ones-MFMA (row-sum in O's lane layout; no psum shuffles/bpermute).
//  - exp2 with folded scale: max over raw scores, p = exp2(fma(raw, sc2, -m)).
template <bool CAUSAL>
__global__ __launch_bounds__(256)
void k_attn6(const bf16* __restrict__ Qb, int ldq,
             const bf16* __restrict__ Kb, int ldkv, int kcol0,
             const bf16* __restrict__ VTg, int Tkv,
             int qlen, int kvlen,
             bf16* __restrict__ Ob, int ldo, float sc2) {
  const int tid = threadIdx.x;
  const int lane = tid & 63;
  const int w = tid >> 6;
  const int lr = lane & 15, lg = lane >> 4;

  int id = blockIdx.x;
  int h, b, qt;
  if (CAUSAL) {
    int low = id & 255;
    h = low & 15; b = (low >> 4) & 1;
    int q3 = low >> 5;
    qt = (id >> 8) ? (8 + q3) : (7 - q3);
  } else {
    h = id & 15; b = (id >> 4) & 1; qt = id >> 5;
  }
  const int hb = (b << 4) | h;

  const int qbase = qt * 128;
  const int kvbase = b * kvlen;
  const int nkv = CAUSAL ? (2 * qt + 2) : (kvlen >> 6);
  const int mask_from = CAUSAL ? (nkv - 2) : 0x7fffffff;

  bf16x8 qf[2][2];
#pragma unroll
  for (int g = 0; g < 2; ++g)
#pragma unroll
    for (int kk = 0; kk < 2; ++kk)
      qf[g][kk] = *(const bf16x8*)(Qb + (size_t)(b * qlen + qbase + w * 32 + g * 16 + lr) * ldq
                                   + h * 64 + kk * 32 + lg * 8);

  __shared__ __align__(16) char Klds[2][8192];   // K rows [kv][128B], XOR-swz image
  __shared__ __align__(16) char Vlds[2][8192];   // V^T rows [d][128B = 64 kv], XOR-swz image

  f32x4 o[2][4] = {};
  f32x4 ls[2] = {};
  float mrun[2] = {-1.0e30f, -1.0e30f};   // scaled-log2 units

  bf16x8 ones;
#pragma unroll
  for (int i = 0; i < 8; ++i) ones[i] = (bf16)1.0f;

  const int sr = tid >> 3;           // 0..31 staging row
  const int pb = (tid & 7) * 16;     // byte chunk in row
  const bf16* Vslab = VTg + (size_t)hb * 64 * Tkv;

  auto stageK = [&](int buf, int kvt) {
#pragma unroll
    for (int t = 0; t < 2; ++t) {
      int r = t * 32 + sr;
      const char* gs = (const char*)(Kb + (size_t)(kvbase + kvt * 64 + r) * ldkv + kcol0 + h * 64)
                       + (pb ^ ((r & 7) << 4));
      gll16(gs, &Klds[buf][t * 4096 + tid * 16]);
    }
  };
  auto stageV = [&](int buf, int kvt) {
#pragma unroll
    for (int t = 0; t < 2; ++t) {
      int r = t * 32 + sr;   // d row
      const char* gs = (const char*)(Vslab + (size_t)r * Tkv + kvt * 64)
                       + (pb ^ ((r & 7) << 4));
      gll16(gs, &Vlds[buf][t * 4096 + tid * 16]);
    }
  };

  stageK(0, 0);
  stageV(0, 0);
  __syncthreads();

  int cur = 0;
  for (int kvt = 0; kvt < nkv; ++kvt) {
    if (kvt + 1 < nkv) { stageK(cur ^ 1, kvt + 1); stageV(cur ^ 1, kvt + 1); }

    // QK^T: s[g][sub][j]: q=lr, kv = sub*16 + lg*4 + j (raw scores)
    f32x4 s[2][4] = {};
    __builtin_amdgcn_s_setprio(1);
#pragma unroll
    for (int sub = 0; sub < 4; ++sub) {
      int row = sub * 16 + lr;
#pragma unroll
      for (int kk = 0; kk < 2; ++kk) {
        bf16x8 kf = *(const bf16x8*)&Klds[cur][(row << 7) + ((kk * 64 + lg * 16) ^ ((row & 7) << 4))];
        s[0][sub] = mfma16(kf, qf[0][kk], s[0][sub]);
        s[1][sub] = mfma16(kf, qf[1][kk], s[1][sub]);
      }
    }
    __builtin_amdgcn_s_setprio(0);

    const bool domask = CAUSAL && (kvt >= mask_from);
    bf16x8 pa[2][2];
#pragma unroll
    for (int g = 0; g < 2; ++g) {
      const int qg = qbase + w * 32 + g * 16 + lr;
      float pmax = -1.0e37f;
#pragma unroll
      for (int sub = 0; sub < 4; ++sub)
#pragma unroll
        for (int j = 0; j < 4; ++j) {
          float v = s[g][sub][j];
          if (domask) {
            int kvg = kvt * 64 + sub * 16 + lg * 4 + j;
            if (kvg > qg) { v = -1.0e37f; s[g][sub][j] = v; }
          }
          pmax = fmaxf(pmax, v);
        }
      pmax = fmaxf(pmax, __shfl_xor(pmax, 16, 64));
      pmax = fmaxf(pmax, __shfl_xor(pmax, 32, 64));
      const float pm2 = pmax * sc2;          // scaled-log2
      float m = mrun[g];
      if (__any(pm2 - m > 11.f)) {           // defer-max
        float mnew = fmaxf(m, pm2);
        float alpha = exp2f(m - mnew);
        float al[4];
#pragma unroll
        for (int j = 0; j < 4; ++j) {
          int src = (lane & 48) | (lg * 4 + j);
          al[j] = __int_as_float(__builtin_amdgcn_ds_bpermute(src << 2, __float_as_int(alpha)));
        }
#pragma unroll
        for (int dt = 0; dt < 4; ++dt)
#pragma unroll
          for (int j = 0; j < 4; ++j) o[g][dt][j] *= al[j];
#pragma unroll
        for (int j = 0; j < 4; ++j) ls[g][j] *= al[j];
        mrun[g] = mnew;
        m = mnew;
      }
#pragma unroll
      for (int sp = 0; sp < 2; ++sp)
#pragma unroll
        for (int j = 0; j < 4; ++j) {
          pa[g][sp][j]     = (bf16)exp2f(fmaf(s[g][2 * sp][j],     sc2, -m));
          pa[g][sp][4 + j] = (bf16)exp2f(fmaf(s[g][2 * sp + 1][j], sc2, -m));
        }
    }

    // V^T fragments from swizzled LDS: vf[jj] = V[kv = sp*32 + (jj>>2)*16 + lg*4 + (jj&3)][d]
    bf16x8 vfr[2][4];
#pragma unroll
    for (int sp = 0; sp < 2; ++sp)
#pragma unroll
      for (int dt = 0; dt < 4; ++dt) {
        int d = dt * 16 + lr;
        int swz = (d & 7) << 4;
        bf16x4 va  = *(const bf16x4*)&Vlds[cur][(d << 7) + ((sp * 64 + lg * 8) ^ swz)];
        bf16x4 vb2 = *(const bf16x4*)&Vlds[cur][(d << 7) + ((sp * 64 + 32 + lg * 8) ^ swz)];
        vfr[sp][dt] = __builtin_shufflevector(va, vb2, 0, 1, 2, 3, 4, 5, 6, 7);
      }

    __builtin_amdgcn_s_setprio(1);
#pragma unroll
    for (int sp = 0; sp < 2; ++sp)
#pragma unroll
      for (int dt = 0; dt < 4; ++dt) {
        o[0][dt] = mfma16(pa[0][sp], vfr[sp][dt], o[0][dt]);
        o[1][dt] = mfma16(pa[1][sp], vfr[sp][dt], o[1][dt]);
      }
    ls[0] = mfma16(pa[0][0], ones, ls[0]);
    ls[0] = mfma16(pa[0][1], ones, ls[0]);
    ls[1] = mfma16(pa[1][0], ones, ls[1]);
    ls[1] = mfma16(pa[1][1], ones, ls[1]);
    __builtin_amdgcn_s_setprio(0);

    __syncthreads();
    cur ^= 1;
  }

  // finalize: ls already in O's (q,d) lane layout
#pragma unroll
  for (int g = 0; g < 2; ++g)
#pragma unroll
    for (int dt = 0; dt < 4; ++dt)
#pragma unroll
      for (int j = 0; j < 4; ++j) {
        int gq = b * qlen + qbase + w * 32 + g * 16 + lg * 4 + j;
        Ob[(size_t)gq * ldo + h * 64 + dt * 16 + lr] = (bf16)(o[g][dt][j] / ls[g][j]);
      }
}

// ---------------- host orchestration ----------------
extern "C" void kernel_launch(void* const* d_in, const int* in_sizes, int n_in,
                              void* d_out, int out_size, void* d_ws, size_t ws_size,
                              hipStream_t stream) {
  (void)in_sizes; (void)n_in; (void)out_size; (void)ws_size;
  const float* x        = (const float*)d_in[0];
  const float* plan     = (const float*)d_in[1];
  const float* ln1_g    = (const float*)d_in[2];
  const float* ln1_b    = (const float*)d_in[3];
  const float* c_attn_w = (const float*)d_in[4];
  const float* c_attn_b = (const float*)d_in[5];
  const float* aproj_w  = (const float*)d_in[6];
  const float* aproj_b  = (const float*)d_in[7];
  const float* ln2_g    = (const float*)d_in[8];
  const float* ln2_b    = (const float*)d_in[9];
  const float* q_w      = (const float*)d_in[10];
  const float* q_b      = (const float*)d_in[11];
  const float* k_w      = (const float*)d_in[12];
  const float* k_b      = (const float*)d_in[13];
  const float* v_w      = (const float*)d_in[14];
  const float* v_b      = (const float*)d_in[15];
  const float* ca_w     = (const float*)d_in[16];
  const float* ca_b     = (const float*)d_in[17];
  const float* ln3_g    = (const float*)d_in[18];
  const float* ln3_b    = (const float*)d_in[19];
  const float* fc_w     = (const float*)d_in[20];
  const float* fc_b     = (const float*)d_in[21];
  const float* mp_w     = (const float*)d_in[22];
  const float* mp_b     = (const float*)d_in[23];

  char* ws = (char*)d_ws;
  bf16*  wbuf   = (bf16*)(ws);                        // 8 MiB rotating W^T
  bf16*  lnb    = (bf16*)(ws + (8ull << 20));         // 8 MiB LN output
  bf16*  planb  = (bf16*)(ws + (16ull << 20));        // 2 MiB plan bf16
  bf16*  yb     = (bf16*)(ws + (18ull << 20));        // 8 MiB attn output
  char*  rega   = ws + (26ull << 20);                 // 32 MiB region (qkv+vts | qx+kv+vtx | hmid)
  float* biaskv = (float*)(ws + (58ull << 20));       // 8 KiB
  bf16* qkv  = (bf16*)rega;                           // 24 MiB
  bf16* vts  = (bf16*)(rega + (24ull << 20));         // 8 MiB V^T self [32][64][2048]
  bf16* qx   = (bf16*)rega;                           // 8 MiB
  bf16* kvc  = (bf16*)(rega + (8ull << 20));          // 4 MiB
  bf16* vtx  = (bf16*)(rega + (12ull << 20));         // 2 MiB V^T cross [32][64][512]
  bf16* hmid = (bf16*)rega;                           // 32 MiB
  float* xw = (float*)d_out;   // running residual stream (fp32)

  const float SC2 = 0.125f * 1.4426950408889634f;  // scale * log2(e)
  dim3 wtb(32, 8);

  k_copy_f32<<<4096, 256, 0, stream>>>(x, xw, 1048576);
  k_conv_bf16<<<1024, 256, 0, stream>>>(plan, planb, 262144);
  k_concat2<<<8, 256, 0, stream>>>(k_b, v_b, biaskv, 1024);

  // ----- self-attention -----
  k_ln<<<4096, 256, 0, stream>>>(xw, ln1_g, ln1_b, lnb);
  k_wt<<<dim3(96, 32), wtb, 0, stream>>>(c_attn_w, wbuf, 1024, 3072);
  k_gemm8<0><<<192, 512, 0, stream>>>(lnb, wbuf, c_attn_b, qkv, 4096, 3072, 1024);
  k_vt<<<dim3(64, 2, 32), wtb, 0, stream>>>(qkv, 3072, 2048, 2048, vts);
  k_attn6<true><<<512, 256, 0, stream>>>(qkv, 3072, qkv, 3072, 1024, vts, 2048,
                                         2048, 2048, yb, 1024, SC2);
  k_wt<<<dim3(32, 32), wtb, 0, stream>>>(aproj_w, wbuf, 1024, 1024);
  k_gemm_s<1><<<512, 256, 0, stream>>>(yb, wbuf, aproj_b, xw, 4096, 1024, 1024);

  // ----- cross-attention -----
  k_ln<<<4096, 256, 0, stream>>>(xw, ln2_g, ln2_b, lnb);
  k_wt<<<dim3(32, 32), wtb, 0, stream>>>(q_w, wbuf, 1024, 1024);
  k_gemm_s<0><<<512, 256, 0, stream>>>(lnb, wbuf, q_b, qx, 4096, 1024, 1024);
  k_wt<<<dim3(32, 32), wtb, 0, stream>>>(k_w, wbuf, 1024, 1024);
  k_wt<<<dim3(32, 32), wtb, 0, stream>>>(v_w, wbuf + 1024 * 1024, 1024, 1024);
  k_gemm_s<0><<<256, 256, 0, stream>>>(planb, wbuf, biaskv, kvc, 1024, 2048, 1024);
  k_vt<<<dim3(16, 2, 32), wtb, 0, stream>>>(kvc, 2048, 1024, 512, vtx);
  k_attn6<false><<<512, 256, 0, stream>>>(qx, 1024, kvc, 2048, 0, vtx, 512,
                                          2048, 512, yb, 1024, SC2);
  k_wt<<<dim3(32, 32), wtb, 0, stream>>>(ca_w, wbuf, 1024, 1024);
  k_gemm_s<1><<<512, 256, 0, stream>>>(yb, wbuf, ca_b, xw, 4096, 1024, 1024);

  // ----- MLP -----
  k_ln<<<4096, 256, 0, stream>>>(xw, ln3_g, ln3_b, lnb);
  k_wt<<<dim3(128, 32), wtb, 0, stream>>>(fc_w, wbuf, 1024, 4096);
  k_gemm8<2><<<256, 512, 0, stream>>>(lnb, wbuf, fc_b, hmid, 4096, 4096, 1024);
  k_wt<<<dim3(32, 128), wtb, 0, stream>>>(mp_w, wbuf, 4096, 1024);
  k_gemm_s<1><<<512, 256, 0, stream>>>(hmid, wbuf, mp_b, xw, 4096, 1024, 4096);
}

// Round 9
// 374.936 us; speedup vs baseline: 1.7301x; 1.0364x over previous
//
#include <hip/hip_runtime.h>
#include <stdint.h>

typedef __bf16 bf16;
typedef __bf16 bf16x4 __attribute__((ext_vector_type(4)));
typedef __bf16 bf16x8 __attribute__((ext_vector_type(8)));
typedef float  f32x4  __attribute__((ext_vector_type(4)));

#define DEVI __device__ __forceinline__

DEVI void gll16(const void* g, void* l) {
  __builtin_amdgcn_global_load_lds(
      (const __attribute__((address_space(1))) void*)g,
      (__attribute__((address_space(3))) void*)l,
      16, 0, 0);
}

DEVI f32x4 mfma16(bf16x8 a, bf16x8 b, f32x4 c) {
  return __builtin_amdgcn_mfma_f32_16x16x32_bf16(a, b, c, 0, 0, 0);
}

// ---------------- elementwise ----------------
__global__ void k_copy_f32(const float* __restrict__ in, float* __restrict__ out, int n4) {
  int i = blockIdx.x * 256 + threadIdx.x;
  if (i < n4) ((f32x4*)out)[i] = ((const f32x4*)in)[i];
}

__global__ void k_conv_bf16(const float* __restrict__ in, bf16* __restrict__ out, int n4) {
  int i = blockIdx.x * 256 + threadIdx.x;
  if (i < n4) {
    f32x4 v = ((const f32x4*)in)[i];
    bf16x4 o;
    o[0] = (bf16)v[0]; o[1] = (bf16)v[1]; o[2] = (bf16)v[2]; o[3] = (bf16)v[3];
    ((bf16x4*)out)[i] = o;
  }
}

__global__ void k_concat2(const float* __restrict__ a, const float* __restrict__ b,
                          float* __restrict__ out, int n) {
  int i = blockIdx.x * 256 + threadIdx.x;
  if (i < n) out[i] = a[i];
  else if (i < 2 * n) out[i] = b[i - n];
}

// ------------- weight fp32 [K][N] -> bf16 W^T [N][K], 64x64 tile -------------
// block (64,4): loads 256B/row coalesced, stores 128B contiguous per n-row.
__global__ void k_wt(const float* __restrict__ W, bf16* __restrict__ WT, int K, int N) {
  __shared__ float t[64][65];
  int bn = blockIdx.x * 64, bk = blockIdx.y * 64;
  int tx = threadIdx.x, ty = threadIdx.y;
#pragma unroll
  for (int i = 0; i < 16; ++i)
    t[ty + i * 4][tx] = W[(size_t)(bk + ty + i * 4) * N + bn + tx];
  __syncthreads();
#pragma unroll
  for (int i = 0; i < 16; ++i)
    WT[(size_t)(bn + ty + i * 4) * K + bk + tx] = (bf16)t[tx][ty + i * 4];
}

// ---------------- layernorm (C=1024) fp32 -> bf16 ----------------
__global__ __launch_bounds__(256)
void k_ln(const float* __restrict__ x, const float* __restrict__ g,
          const float* __restrict__ b, bf16* __restrict__ out) {
  int row = blockIdx.x, tid = threadIdx.x;
  f32x4 v = ((const f32x4*)(x + (size_t)row * 1024))[tid];
  float s = v[0] + v[1] + v[2] + v[3];
  float sq = v[0]*v[0] + v[1]*v[1] + v[2]*v[2] + v[3]*v[3];
#pragma unroll
  for (int m = 1; m < 64; m <<= 1) {
    s  += __shfl_xor(s, m, 64);
    sq += __shfl_xor(sq, m, 64);
  }
  __shared__ float ps[4], psq[4];
  int w = tid >> 6;
  if ((tid & 63) == 0) { ps[w] = s; psq[w] = sq; }
  __syncthreads();
  s  = ps[0] + ps[1] + ps[2] + ps[3];
  sq = psq[0] + psq[1] + psq[2] + psq[3];
  float mean = s * (1.f / 1024.f);
  float rs = rsqrtf(sq * (1.f / 1024.f) - mean * mean + 1e-5f);
  f32x4 gv = ((const f32x4*)g)[tid];
  f32x4 bv = ((const f32x4*)b)[tid];
  bf16x4 o;
#pragma unroll
  for (int i = 0; i < 4; ++i) o[i] = (bf16)((v[i] - mean) * rs * gv[i] + bv[i]);
  ((bf16x4*)(out + (size_t)row * 1024))[tid] = o;
}

// ---------------- GEMM small-tile: BM=64 BN=128 BK=64, 2-phase, 3 blk/CU ----------------
template <int EPI>
__global__ __launch_bounds__(256, 3)
void k_gemm_s(const bf16* __restrict__ A, const bf16* __restrict__ BT,
              const float* __restrict__ bias, void* __restrict__ Cout,
              int M, int N, int K) {
  __shared__ __align__(16) char SA[2][8192];
  __shared__ __align__(16) char SB[2][16384];
  const int tid = threadIdx.x;
  const int lane = tid & 63;
  const int w = tid >> 6;
  const int wr = w >> 1, wc = w & 1;
  const int lr = lane & 15, lg = lane >> 4;
  const int nk = K >> 6;

  const int nwg = gridDim.x;
  const int q = nwg >> 3, r = nwg & 7;
  const int xcd = blockIdx.x & 7, loc = blockIdx.x >> 3;
  const int wg = (xcd < r ? xcd * (q + 1) : r * (q + 1) + (xcd - r) * q) + loc;
  const int gy = M >> 6;
  const int m0 = (wg % gy) << 6, n0 = (wg / gy) << 7;

  const int c8 = tid & 7;
  const int hrb = tid >> 3;
  auto stgA = [&](int buf, int ktc) {
#pragma unroll
    for (int i = 0; i < 2; ++i) {
      int hr = i * 32 + hrb;
      const bf16* s = A + (size_t)(m0 + hr) * K + ((size_t)ktc << 6) + ((c8 ^ (hr & 7)) << 3);
      gll16(s, &SA[buf][(i * 256 + tid) * 16]);
    }
  };
  auto stgB = [&](int buf, int ktc) {
#pragma unroll
    for (int i = 0; i < 4; ++i) {
      int hr = i * 32 + hrb;
      const bf16* s = BT + (size_t)(n0 + hr) * K + ((size_t)ktc << 6) + ((c8 ^ (hr & 7)) << 3);
      gll16(s, &SB[buf][(i * 256 + tid) * 16]);
    }
  };
  auto rdf = [&](const char* base, int rloc, int ks) -> bf16x8 {
    return *(const bf16x8*)(base + rloc * 128 + (((ks << 6) + (lg << 4)) ^ ((rloc & 7) << 4)));
  };

  f32x4 acc[2][4] = {};

  stgA(0, 0); stgB(0, 0);
  __syncthreads();
  for (int kt = 0; kt < nk; ++kt) {
    const int cur = kt & 1;
    if (kt + 1 < nk) { stgA(cur ^ 1, kt + 1); stgB(cur ^ 1, kt + 1); }
    bf16x8 af[2][2], bfr[4][2];
#pragma unroll
    for (int i = 0; i < 2; ++i)
#pragma unroll
      for (int ks = 0; ks < 2; ++ks)
        af[i][ks] = rdf(SA[cur], wr * 32 + i * 16 + lr, ks);
#pragma unroll
    for (int j = 0; j < 4; ++j)
#pragma unroll
      for (int ks = 0; ks < 2; ++ks)
        bfr[j][ks] = rdf(SB[cur], wc * 64 + j * 16 + lr, ks);
#pragma unroll
    for (int i = 0; i < 2; ++i)
#pragma unroll
      for (int j = 0; j < 4; ++j)
#pragma unroll
        for (int ks = 0; ks < 2; ++ks)
          acc[i][j] = mfma16(af[i][ks], bfr[j][ks], acc[i][j]);
    __syncthreads();
  }

  float* of = (float*)Cout;
  bf16*  ob = (bf16*)Cout;
#pragma unroll
  for (int j = 0; j < 4; ++j) {
    int gn = n0 + wc * 64 + j * 16 + lr;
    float bv = bias[gn];
#pragma unroll
    for (int i = 0; i < 2; ++i) {
      int gmb = m0 + wr * 32 + i * 16 + lg * 4;
#pragma unroll
      for (int rr = 0; rr < 4; ++rr) {
        size_t idx = (size_t)(gmb + rr) * N + gn;
        float v = acc[i][j][rr] + bv;
        if (EPI == 0) ob[idx] = (bf16)v;
        else if (EPI == 1) of[idx] += v;
        else {
          float ge = 0.5f * v * (1.f + erff(v * 0.70710678f));
          ob[idx] = (bf16)ge;
        }
      }
    }
  }
}

// ---------------- GEMM split-K=2, BM=64 BN=128 BK=64, atomic fp32 accumulate ----------------
// For mlp_proj (K=4096): blockIdx.y = K-split; bias added by split 0 only.
__global__ __launch_bounds__(256, 3)
void k_gemm_sk(const bf16* __restrict__ A, const bf16* __restrict__ BT,
               const float* __restrict__ bias, float* __restrict__ Cout,
               int M, int N, int K) {
  __shared__ __align__(16) char SA[2][8192];
  __shared__ __align__(16) char SB[2][16384];
  const int tid = threadIdx.x;
  const int lane = tid & 63;
  const int w = tid >> 6;
  const int wr = w >> 1, wc = w & 1;
  const int lr = lane & 15, lg = lane >> 4;
  const int nk2 = K >> 7;                 // K-steps per split
  const int kbeg = blockIdx.y * nk2;

  const int nwg = gridDim.x;
  const int q = nwg >> 3, r = nwg & 7;
  const int xcd = blockIdx.x & 7, loc = blockIdx.x >> 3;
  const int wg = (xcd < r ? xcd * (q + 1) : r * (q + 1) + (xcd - r) * q) + loc;
  const int gy = M >> 6;
  const int m0 = (wg % gy) << 6, n0 = (wg / gy) << 7;

  const int c8 = tid & 7;
  const int hrb = tid >> 3;
  auto stgA = [&](int buf, int ktc) {
#pragma unroll
    for (int i = 0; i < 2; ++i) {
      int hr = i * 32 + hrb;
      const bf16* s = A + (size_t)(m0 + hr) * K + ((size_t)ktc << 6) + ((c8 ^ (hr & 7)) << 3);
      gll16(s, &SA[buf][(i * 256 + tid) * 16]);
    }
  };
  auto stgB = [&](int buf, int ktc) {
#pragma unroll
    for (int i = 0; i < 4; ++i) {
      int hr = i * 32 + hrb;
      const bf16* s = BT + (size_t)(n0 + hr) * K + ((size_t)ktc << 6) + ((c8 ^ (hr & 7)) << 3);
      gll16(s, &SB[buf][(i * 256 + tid) * 16]);
    }
  };
  auto rdf = [&](const char* base, int rloc, int ks) -> bf16x8 {
    return *(const bf16x8*)(base + rloc * 128 + (((ks << 6) + (lg << 4)) ^ ((rloc & 7) << 4)));
  };

  f32x4 acc[2][4] = {};

  stgA(0, kbeg); stgB(0, kbeg);
  __syncthreads();
  for (int it = 0; it < nk2; ++it) {
    const int cur = it & 1;
    if (it + 1 < nk2) { stgA(cur ^ 1, kbeg + it + 1); stgB(cur ^ 1, kbeg + it + 1); }
    bf16x8 af[2][2], bfr[4][2];
#pragma unroll
    for (int i = 0; i < 2; ++i)
#pragma unroll
      for (int ks = 0; ks < 2; ++ks)
        af[i][ks] = rdf(SA[cur], wr * 32 + i * 16 + lr, ks);
#pragma unroll
    for (int j = 0; j < 4; ++j)
#pragma unroll
      for (int ks = 0; ks < 2; ++ks)
        bfr[j][ks] = rdf(SB[cur], wc * 64 + j * 16 + lr, ks);
#pragma unroll
    for (int i = 0; i < 2; ++i)
#pragma unroll
      for (int j = 0; j < 4; ++j)
#pragma unroll
        for (int ks = 0; ks < 2; ++ks)
          acc[i][j] = mfma16(af[i][ks], bfr[j][ks], acc[i][j]);
    __syncthreads();
  }

#pragma unroll
  for (int j = 0; j < 4; ++j) {
    int gn = n0 + wc * 64 + j * 16 + lr;
    float bv = (blockIdx.y == 0) ? bias[gn] : 0.0f;
#pragma unroll
    for (int i = 0; i < 2; ++i) {
      int gmb = m0 + wr * 32 + i * 16 + lg * 4;
#pragma unroll
      for (int rr = 0; rr < 4; ++rr) {
        size_t idx = (size_t)(gmb + rr) * N + gn;
        atomicAdd(&Cout[idx], acc[i][j][rr] + bv);
      }
    }
  }
}

// ---------------- GEMM 256x256 8-phase counted-vmcnt (T2+T3+T4+T5) ----------------
template <int EPI>
__global__ __launch_bounds__(512, 2)
void k_gemm8(const bf16* __restrict__ A, const bf16* __restrict__ BT,
             const float* __restrict__ bias, void* __restrict__ Cout,
             int M, int N, int K) {
  __shared__ __align__(16) char SA[2][2][16384];
  __shared__ __align__(16) char SB[2][2][16384];
  const int tid = threadIdx.x;
  const int lane = tid & 63;
  const int w = tid >> 6;
  const int wm = w >> 2, wn = w & 3;
  const int lr = lane & 15, lg = lane >> 4;
  const int nk = K >> 6;

  const int nwg = gridDim.x;
  const int q = nwg >> 3, r = nwg & 7;
  const int xcd = blockIdx.x & 7, loc = blockIdx.x >> 3;
  const int wg = (xcd < r ? xcd * (q + 1) : r * (q + 1) + (xcd - r) * q) + loc;
  const int gy = M >> 8;
  const int m0 = (wg % gy) << 8, n0 = (wg / gy) << 8;

  const int c8 = tid & 7;
  auto stg = [&](char* dst, const bf16* src0, int base0, int half, int ktc) {
#pragma unroll
    for (int i = 0; i < 2; ++i) {
      int hr = i * 64 + (tid >> 3);
      const bf16* s = src0 + (size_t)(base0 + half * 128 + hr) * K + ((size_t)ktc << 6)
                    + ((c8 ^ (hr & 7)) << 3);
      gll16(s, dst + (i * 512 + tid) * 16);
    }
  };
  auto rdf = [&](const char* hbase, int rloc, int ks) -> bf16x8 {
    return *(const bf16x8*)(hbase + rloc * 128 + (((ks << 6) + (lg << 4)) ^ ((rloc & 7) << 4)));
  };

  f32x4 acc[8][4] = {};
  bf16x8 af[4][2], b0f[2][2], b1f[2][2];

  stg(SA[0][0], A, m0, 0, 0);
  stg(SB[0][0], BT, n0, 0, 0);
  stg(SB[0][1], BT, n0, 1, 0);
  stg(SA[0][1], A, m0, 1, 0);
  stg(SA[1][0], A, m0, 0, 1);
  stg(SB[1][0], BT, n0, 0, 1);
  asm volatile("s_waitcnt vmcnt(8)" ::: "memory");
  __builtin_amdgcn_s_barrier();

  for (int kt = 0; kt < nk; ++kt) {
    const int cur = kt & 1;
    const char* hA0 = SA[cur][0]; const char* hA1 = SA[cur][1];
    const char* hB0 = SB[cur][0]; const char* hB1 = SB[cur][1];
    const int tn  = (kt + 1 < nk) ? kt + 1 : nk - 1;
    const int tn2 = (kt + 2 < nk) ? kt + 2 : nk - 1;

    stg(SB[(kt + 1) & 1][1], BT, n0, 1, tn);
    asm volatile("s_waitcnt vmcnt(8)" ::: "memory");
#pragma unroll
    for (int i = 0; i < 4; ++i) {
      int rl = i * 32 + wm * 16 + lr;
#pragma unroll
      for (int ks = 0; ks < 2; ++ks) af[i][ks] = rdf(hA0, rl, ks);
    }
#pragma unroll
    for (int j = 0; j < 2; ++j) {
      int rl = j * 64 + wn * 16 + lr;
#pragma unroll
      for (int ks = 0; ks < 2; ++ks) b0f[j][ks] = rdf(hB0, rl, ks);
    }
    __builtin_amdgcn_s_barrier();
    __builtin_amdgcn_s_setprio(1);
#pragma unroll
    for (int i = 0; i < 4; ++i)
#pragma unroll
      for (int j = 0; j < 2; ++j)
#pragma unroll
        for (int ks = 0; ks < 2; ++ks)
          acc[i][j] = mfma16(af[i][ks], b0f[j][ks], acc[i][j]);
    __builtin_amdgcn_s_setprio(0);

    stg(SA[(kt + 1) & 1][1], A, m0, 1, tn);
    asm volatile("s_waitcnt vmcnt(8)" ::: "memory");
#pragma unroll
    for (int j = 0; j < 2; ++j) {
      int rl = j * 64 + wn * 16 + lr;
#pragma unroll
      for (int ks = 0; ks < 2; ++ks) b1f[j][ks] = rdf(hB1, rl, ks);
    }
    __builtin_amdgcn_s_barrier();
    __builtin_amdgcn_s_setprio(1);
#pragma unroll
    for (int i = 0; i < 4; ++i)
#pragma unroll
      for (int j = 0; j < 2; ++j)
#pragma unroll
        for (int ks = 0; ks < 2; ++ks)
          acc[i][2 + j] = mfma16(af[i][ks], b1f[j][ks], acc[i][2 + j]);
    __builtin_amdgcn_s_setprio(0);

    stg(SA[cur][0], A, m0, 0, tn2);
#pragma unroll
    for (int i = 0; i < 4; ++i) {
      int rl = i * 32 + wm * 16 + lr;
#pragma unroll
      for (int ks = 0; ks < 2; ++ks) af[i][ks] = rdf(hA1, rl, ks);
    }
    __builtin_amdgcn_s_barrier();
    __builtin_amdgcn_s_setprio(1);
#pragma unroll
    for (int i = 0; i < 4; ++i)
#pragma unroll
      for (int j = 0; j < 2; ++j)
#pragma unroll
        for (int ks = 0; ks < 2; ++ks)
          acc[4 + i][j] = mfma16(af[i][ks], b0f[j][ks], acc[4 + i][j]);
    __builtin_amdgcn_s_setprio(0);

    stg(SB[cur][0], BT, n0, 0, tn2);
    asm volatile("s_waitcnt vmcnt(8)" ::: "memory");
    __builtin_amdgcn_s_barrier();
    __builtin_amdgcn_s_setprio(1);
#pragma unroll
    for (int i = 0; i < 4; ++i)
#pragma unroll
      for (int j = 0; j < 2; ++j)
#pragma unroll
        for (int ks = 0; ks < 2; ++ks)
          acc[4 + i][2 + j] = mfma16(af[i][ks], b1f[j][ks], acc[4 + i][2 + j]);
    __builtin_amdgcn_s_setprio(0);
  }

  float* of = (float*)Cout;
  bf16*  ob = (bf16*)Cout;
#pragma unroll
  for (int ni = 0; ni < 4; ++ni) {
    int gn = n0 + (ni >> 1) * 128 + (ni & 1) * 64 + wn * 16 + lr;
    float bv = bias[gn];
#pragma unroll
    for (int mi = 0; mi < 8; ++mi) {
      int gmb = m0 + (mi >> 2) * 128 + (mi & 3) * 32 + wm * 16 + lg * 4;
#pragma unroll
      for (int rr = 0; rr < 4; ++rr) {
        size_t idx = (size_t)(gmb + rr) * N + gn;
        float v = acc[mi][ni][rr] + bv;
        if (EPI == 0) ob[idx] = (bf16)v;
        else if (EPI == 1) of[idx] += v;
        else {
          float ge = 0.5f * v * (1.f + erff(v * 0.70710678f));
          ob[idx] = (bf16)ge;
        }
      }
    }
  }
}

// ---------------- fused flash attention v2 (r4 champion, verbatim) ----------------
template <bool CAUSAL>
__global__ __launch_bounds__(256)
void k_attn2(const bf16* __restrict__ Qb, int ldq, int qcol0,
             const bf16* __restrict__ Kb, int kcol0,
             const bf16* __restrict__ Vb, int vcol0,
             int ldkv, int qlen, int kvlen,
             bf16* __restrict__ Ob, int ldo, float scale) {
  const int tid = threadIdx.x;
  const int lane = tid & 63;
  const int w = tid >> 6;
  const int lr = lane & 15, lg = lane >> 4;

  int id = blockIdx.x;
  int h, b, qt;
  if (CAUSAL) {
    int low = id & 255;
    h = low & 15; b = (low >> 4) & 1;
    int q3 = low >> 5;
    qt = (id >> 8) ? (8 + q3) : (7 - q3);
  } else {
    h = id & 15; b = (id >> 4) & 1; qt = id >> 5;
  }

  const int qbase = qt * 128;
  const int kvbase = b * kvlen;
  const int nkv = CAUSAL ? (2 * qt + 2) : (kvlen >> 6);
  const int mask_from = CAUSAL ? (nkv - 2) : 0x7fffffff;

  bf16x8 qf[2][2];
#pragma unroll
  for (int g = 0; g < 2; ++g)
#pragma unroll
    for (int kk = 0; kk < 2; ++kk)
      qf[g][kk] = *(const bf16x8*)(Qb + (size_t)(b * qlen + qbase + w * 32 + g * 16 + lr) * ldq
                                   + qcol0 + h * 64 + kk * 32 + lg * 8);

  __shared__ __align__(16) char Klds[2][8192];
  __shared__ __align__(16) bf16 VT[2][64][68];

  f32x4 o[2][4] = {};
  float mrun[2] = {-3.0e38f, -3.0e38f};
  float lsum[2] = {0.f, 0.f};

  bf16x8 vr0, vr1;
  const int vkv = lane;
  const int vd0 = (tid >> 6) * 16;
  const bf16* Vbase = Vb + vcol0 + h * 64 + vd0;

  auto stageK = [&](int buf, int kvt) {
#pragma unroll
    for (int t = 0; t < 2; ++t) {
      int r = t * 32 + (tid >> 3);
      int pb = (tid & 7) * 16;
      const char* gs = (const char*)(Kb + (size_t)(kvbase + kvt * 64 + r) * ldkv + kcol0 + h * 64)
                       + (pb ^ ((r & 7) << 4));
      gll16(gs, &Klds[buf][t * 4096 + tid * 16]);
    }
  };
  auto loadV = [&](int kvt) {
    const bf16* vp = Vbase + (size_t)(kvbase + kvt * 64 + vkv) * ldkv;
    vr0 = *(const bf16x8*)vp;
    vr1 = *(const bf16x8*)(vp + 8);
  };
  auto writeV = [&](int buf) {
#pragma unroll
    for (int i = 0; i < 8; ++i) VT[buf][vd0 + i][vkv] = vr0[i];
#pragma unroll
    for (int i = 0; i < 8; ++i) VT[buf][vd0 + 8 + i][vkv] = vr1[i];
  };

  stageK(0, 0);
  loadV(0);
  writeV(0);
  __syncthreads();

  int cur = 0;
  for (int kvt = 0; kvt < nkv; ++kvt) {
    if (kvt + 1 < nkv) { stageK(cur ^ 1, kvt + 1); loadV(kvt + 1); }

    f32x4 s[2][4] = {};
#pragma unroll
    for (int sub = 0; sub < 4; ++sub) {
      int row = sub * 16 + lr;
#pragma unroll
      for (int kk = 0; kk < 2; ++kk) {
        bf16x8 kf = *(const bf16x8*)&Klds[cur][(row << 7) + ((kk * 64 + lg * 16) ^ ((row & 7) << 4))];
        s[0][sub] = mfma16(kf, qf[0][kk], s[0][sub]);
        s[1][sub] = mfma16(kf, qf[1][kk], s[1][sub]);
      }
    }

    const bool domask = CAUSAL && (kvt >= mask_from);
    bf16x8 pa[2][2];
#pragma unroll
    for (int g = 0; g < 2; ++g) {
      const int qg = qbase + w * 32 + g * 16 + lr;
      float pmax = -3.0e38f;
#pragma unroll
      for (int sub = 0; sub < 4; ++sub)
#pragma unroll
        for (int j = 0; j < 4; ++j) {
          float v = s[g][sub][j] * scale;
          if (domask) {
            int kvg = kvt * 64 + sub * 16 + lg * 4 + j;
            if (kvg > qg) v = -3.0e38f;
          }
          s[g][sub][j] = v;
          pmax = fmaxf(pmax, v);
        }
      pmax = fmaxf(pmax, __shfl_xor(pmax, 16, 64));
      pmax = fmaxf(pmax, __shfl_xor(pmax, 32, 64));
      float mnew = mrun[g];
      if (__any(pmax - mrun[g] > 8.f)) {
        mnew = fmaxf(mrun[g], pmax);
        float alpha = __expf(mrun[g] - mnew);
        lsum[g] *= alpha;
        float al[4];
#pragma unroll
        for (int j = 0; j < 4; ++j) {
          int src = (lane & 48) | (lg * 4 + j);
          al[j] = __int_as_float(__builtin_amdgcn_ds_bpermute(src << 2, __float_as_int(alpha)));
        }
#pragma unroll
        for (int dt = 0; dt < 4; ++dt)
#pragma unroll
          for (int j = 0; j < 4; ++j) o[g][dt][j] *= al[j];
      }
      float psum = 0.f;
#pragma unroll
      for (int sub = 0; sub < 4; ++sub)
#pragma unroll
        for (int j = 0; j < 4; ++j) {
          float p = __expf(s[g][sub][j] - mnew);
          s[g][sub][j] = p;
          psum += p;
        }
      psum += __shfl_xor(psum, 16, 64);
      psum += __shfl_xor(psum, 32, 64);
      lsum[g] += psum;
      mrun[g] = mnew;
#pragma unroll
      for (int sp = 0; sp < 2; ++sp) {
#pragma unroll
        for (int j = 0; j < 4; ++j) {
          pa[g][sp][j]     = (bf16)s[g][2 * sp][j];
          pa[g][sp][4 + j] = (bf16)s[g][2 * sp + 1][j];
        }
      }
    }

#pragma unroll
    for (int sp = 0; sp < 2; ++sp) {
#pragma unroll
      for (int dt = 0; dt < 4; ++dt) {
        int d = dt * 16 + lr;
        bf16x4 va  = *(const bf16x4*)&VT[cur][d][sp * 32 + lg * 4];
        bf16x4 vb2 = *(const bf16x4*)&VT[cur][d][sp * 32 + 16 + lg * 4];
        bf16x8 vf = __builtin_shufflevector(va, vb2, 0, 1, 2, 3, 4, 5, 6, 7);
        o[0][dt] = mfma16(pa[0][sp], vf, o[0][dt]);
        o[1][dt] = mfma16(pa[1][sp], vf, o[1][dt]);
      }
    }

    if (kvt + 1 < nkv) writeV(cur ^ 1);
    __syncthreads();
    cur ^= 1;
  }

#pragma unroll
  for (int g = 0; g < 2; ++g) {
    float il[4];
#pragma unroll
    for (int j = 0; j < 4; ++j) {
      int src = (lane & 48) | (lg * 4 + j);
      float ls = __int_as_float(__builtin_amdgcn_ds_bpermute(src << 2, __float_as_int(lsum[g])));
      il[j] = 1.0f / ls;
    }
#pragma unroll
    for (int dt = 0; dt < 4; ++dt)
#pragma unroll
      for (int j = 0; j < 4; ++j) {
        int gq = b * qlen + qbase + w * 32 + g * 16 + lg * 4 + j;
        Ob[(size_t)gq * ldo + h * 64 + dt * 16 + lr] = (bf16)(o[g][dt][j] * il[j]);
      }
  }
}

// ---------------- host orchestration ----------------
extern "C" void kernel_launch(void* const* d_in, const int* in_sizes, int n_in,
                              void* d_out, int out_size, void* d_ws, size_t ws_size,
                              hipStream_t stream) {
  (void)in_sizes; (void)n_in; (void)out_size; (void)ws_size;
  const float* x        = (const float*)d_in[0];
  const float* plan     = (const float*)d_in[1];
  const float* ln1_g    = (const float*)d_in[2];
  const float* ln1_b    = (const float*)d_in[3];
  const float* c_attn_w = (const float*)d_in[4];
  const float* c_attn_b = (const float*)d_in[5];
  const float* aproj_w  = (const float*)d_in[6];
  const float* aproj_b  = (const float*)d_in[7];
  const float* ln2_g    = (const float*)d_in[8];
  const float* ln2_b    = (const float*)d_in[9];
  const float* q_w      = (const float*)d_in[10];
  const float* q_b      = (const float*)d_in[11];
  const float* k_w      = (const float*)d_in[12];
  const float* k_b      = (const float*)d_in[13];
  const float* v_w      = (const float*)d_in[14];
  const float* v_b      = (const float*)d_in[15];
  const float* ca_w     = (const float*)d_in[16];
  const float* ca_b     = (const float*)d_in[17];
  const float* ln3_g    = (const float*)d_in[18];
  const float* ln3_b    = (const float*)d_in[19];
  const float* fc_w     = (const float*)d_in[20];
  const float* fc_b     = (const float*)d_in[21];
  const float* mp_w     = (const float*)d_in[22];
  const float* mp_b     = (const float*)d_in[23];

  char* ws = (char*)d_ws;
  bf16*  wbuf   = (bf16*)(ws);                        // 8 MiB rotating W^T
  bf16*  lnb    = (bf16*)(ws + (8ull << 20));         // 8 MiB LN output
  bf16*  planb  = (bf16*)(ws + (16ull << 20));        // 2 MiB plan bf16
  bf16*  yb     = (bf16*)(ws + (18ull << 20));        // 8 MiB attn output
  char*  rega   = ws + (26ull << 20);                 // 32 MiB region (qkv | qx+kv | hmid)
  float* biaskv = (float*)(ws + (58ull << 20));       // 8 KiB
  bf16* qkv  = (bf16*)rega;
  bf16* qx   = (bf16*)rega;
  bf16* kvc  = (bf16*)(rega + (8ull << 20));
  bf16* hmid = (bf16*)rega;
  float* xw = (float*)d_out;   // running residual stream (fp32)

  dim3 wtb(64, 4);

  k_copy_f32<<<4096, 256, 0, stream>>>(x, xw, 1048576);
  k_conv_bf16<<<1024, 256, 0, stream>>>(plan, planb, 262144);
  k_concat2<<<8, 256, 0, stream>>>(k_b, v_b, biaskv, 1024);

  // ----- self-attention -----
  k_ln<<<4096, 256, 0, stream>>>(xw, ln1_g, ln1_b, lnb);
  k_wt<<<dim3(48, 16), wtb, 0, stream>>>(c_attn_w, wbuf, 1024, 3072);
  k_gemm8<0><<<192, 512, 0, stream>>>(lnb, wbuf, c_attn_b, qkv, 4096, 3072, 1024);
  k_attn2<true><<<512, 256, 0, stream>>>(qkv, 3072, 0, qkv, 1024, qkv, 2048,
                                         3072, 2048, 2048, yb, 1024, 0.125f);
  k_wt<<<dim3(16, 16), wtb, 0, stream>>>(aproj_w, wbuf, 1024, 1024);
  k_gemm_s<1><<<512, 256, 0, stream>>>(yb, wbuf, aproj_b, xw, 4096, 1024, 1024);

  // ----- cross-attention -----
  k_ln<<<4096, 256, 0, stream>>>(xw, ln2_g, ln2_b, lnb);
  k_wt<<<dim3(16, 16), wtb, 0, stream>>>(q_w, wbuf, 1024, 1024);
  k_gemm_s<0><<<512, 256, 0, stream>>>(lnb, wbuf, q_b, qx, 4096, 1024, 1024);
  k_wt<<<dim3(16, 16), wtb, 0, stream>>>(k_w, wbuf, 1024, 1024);
  k_wt<<<dim3(16, 16), wtb, 0, stream>>>(v_w, wbuf + 1024 * 1024, 1024, 1024);
  k_gemm_s<0><<<256, 256, 0, stream>>>(planb, wbuf, biaskv, kvc, 1024, 2048, 1024);
  k_attn2<false><<<512, 256, 0, stream>>>(qx, 1024, 0, kvc, 0, kvc, 1024,
                                          2048, 2048, 512, yb, 1024, 0.125f);
  k_wt<<<dim3(16, 16), wtb, 0, stream>>>(ca_w, wbuf, 1024, 1024);
  k_gemm_s<1><<<512, 256, 0, stream>>>(yb, wbuf, ca_b, xw, 4096, 1024, 1024);

  // ----- MLP -----
  k_ln<<<4096, 256, 0, stream>>>(xw, ln3_g, ln3_b, lnb);
  k_wt<<<dim3(64, 16), wtb, 0, stream>>>(fc_w, wbuf, 1024, 4096);
  k_gemm8<2><<<256, 512, 0, stream>>>(lnb, wbuf, fc_b, hmid, 4096, 4096, 1024);
  k_wt<<<dim3(16, 64), wtb, 0, stream>>>(mp_w, wbuf, 4096, 1024);
  k_gemm_sk<<<dim3(512, 2), 256, 0, stream>>>(hmid, wbuf, mp_b, xw, 4096, 1024, 4096);
}